// Round 6
// baseline (770.379 us; speedup 1.0000x reference)
//
#include <hip/hip_runtime.h>
#include <hip/hip_bf16.h>

#define BATCH  64
#define T_ENC  32
#define D_IN   4096
#define T_DEC  20
#define D_WORD 300
#define HID    512
#define FOURH  2048
#define NWG    64
#define ZP     13
// flags layout (u32 idx): [(wg*8+w)*32] per-WAVE step flags (512 lines);
// [CNT_BASE + i*32] i=0..15 enc bx counters, 16..25 dec bx counters,
// 26..45 dcnt[t] (proj gating, target 512 wave-bumps).
#define CNT_BASE 16384
#define FLAGS_N  17856

typedef __attribute__((ext_vector_type(8))) short short8;
typedef __attribute__((ext_vector_type(4))) float f32x4;
typedef unsigned long long ull;

static __device__ __forceinline__ unsigned short f2bf(float f){
  union { float f; unsigned u; } v; v.f = f;
  unsigned r = v.u + 0x7fffu + ((v.u >> 16) & 1u);   // RNE
  return (unsigned short)(r >> 16);
}
static __device__ __forceinline__ float bf2f(unsigned short b){
  union { unsigned u; float f; } v; v.u = ((unsigned)b) << 16;
  return v.f;
}
static __device__ __forceinline__ float sigm(float x){
  return __builtin_amdgcn_rcpf(1.f + __expf(-x));
}
static __device__ __forceinline__ float tanh_f(float x){
  float e = __expf(2.f * x);
  return 1.f - 2.f * __builtin_amdgcn_rcpf(e + 1.f);
}

// ---------------------------------------------------------------------------
// prep: frames -> bf16, W_enc input rows -> bf16 transposed, zero flags,
// zero Xe (fused accumulates via atomicAdd).
// ---------------------------------------------------------------------------
__global__ __launch_bounds__(256) void prep(
    const float* __restrict__ frames, const float* __restrict__ W_enc,
    unsigned short* __restrict__ fb, unsigned short* __restrict__ wt,
    unsigned* __restrict__ flags, float* __restrict__ Xe)
{
  const int g = blockIdx.x * 256 + threadIdx.x;
  if (blockIdx.x == 0){
    for (int i = threadIdx.x; i < FLAGS_N; i += 256)
      __hip_atomic_store(&flags[i], 0u, __ATOMIC_RELAXED, __HIP_MEMORY_SCOPE_AGENT);
  }
  { // zero Xe: 4194304 floats, 2097152 threads -> float2 each
    float2 z2; z2.x = 0.f; z2.y = 0.f;
    *(float2*)(Xe + (long)g * 2) = z2;
  }
  if (g < 1048576){
    const long base = (long)g * 8;
    float4 x0 = *(const float4*)(frames + base);
    float4 x1 = *(const float4*)(frames + base + 4);
    short8 v;
    v[0] = (short)f2bf(x0.x); v[1] = (short)f2bf(x0.y);
    v[2] = (short)f2bf(x0.z); v[3] = (short)f2bf(x0.w);
    v[4] = (short)f2bf(x1.x); v[5] = (short)f2bf(x1.y);
    v[6] = (short)f2bf(x1.z); v[7] = (short)f2bf(x1.w);
    *(short8*)(fb + base) = v;
  } else {
    const int r  = g - 1048576;
    const int k0 = (r >> 11) << 3;       // 0..4088 step 8
    const int c  = r & 2047;             // coalesced reads across c
    short8 v;
#pragma unroll
    for (int j = 0; j < 8; ++j)
      v[j] = (short)f2bf(W_enc[(long)(k0 + j) * FOURH + c]);
    *(short8*)&wt[(long)c * D_IN + k0] = v;
  }
}

// ---------------------------------------------------------------------------
// Encoder tile, 8-wave (512 thr), 128x128, K-chunk = 1024 (BK=64, 16 iters),
// XOR-swizzled LDS, next-iter reg prefetch. Accumulates into Xe via fp32
// atomicAdd, bumps per-bx counter (target 64 = 16 by * 4 kc).
// ---------------------------------------------------------------------------
__device__ __forceinline__ void enc_tile8(
    int bx, int by, int kc,
    const unsigned short* __restrict__ A0, const unsigned short* __restrict__ Wt,
    float* Z, char* smem, unsigned* flags)
{
  char* As = smem;            // [128 rows][128B], byte ^= (row&7)<<4
  char* Bs = smem + 16384;
  const int tid = threadIdx.x;
  const int row0 = bx * 128, col0 = by * 128;

  const int ar = tid >> 2, ah = tid & 3;       // A: 4 thr/row, 16 shorts each
  long asrc;
  {
    int R = row0 + ar;
    int b = R & 63, t = R >> 6;
    asrc = (long)(b * T_ENC + t) * D_IN;
  }
  const int bc = tid & 127, bh = tid >> 7;     // B: 4 thr/col
  const long bsrc = (long)(col0 + bc) * D_IN;
  const long kbase = (long)kc * 1024;

  const int wave = tid >> 6, lane = tid & 63;
  const int wm = (wave >> 2) * 64, wn = (wave & 3) * 32;
  const int lr = lane & 15, lkb = (lane >> 4) << 4, lq = (lane >> 4) << 2;

  f32x4 acc[4][2];
#pragma unroll
  for (int m = 0; m < 4; ++m)
#pragma unroll
    for (int n = 0; n < 2; ++n) acc[m][n] = (f32x4){0.f, 0.f, 0.f, 0.f};

#define ELOAD8(DA, DB, IT) do { \
    const long ka = kbase + (long)(IT) * 64 + ah * 16; \
    const long kb = kbase + (long)(IT) * 64 + bh * 16; \
    _Pragma("unroll") \
    for (int j = 0; j < 2; ++j){ \
      DA[j] = *(const short8*)(A0 + asrc + ka + j * 8); \
      DB[j] = *(const short8*)(Wt + bsrc + kb + j * 8); \
    } \
  } while (0)

  short8 aR[2], bR[2];
  ELOAD8(aR, bR, 0);

  for (int it = 0; it < 16; ++it){
    __syncthreads();   // prev iter's frag reads done
#pragma unroll
    for (int j = 0; j < 2; ++j){
      *(short8*)(As + ar * 128 + ((ah * 32 + j * 16) ^ ((ar & 7) << 4))) = aR[j];
      *(short8*)(Bs + bc * 128 + ((bh * 32 + j * 16) ^ ((bc & 7) << 4))) = bR[j];
    }
    __syncthreads();
    short8 aN[2], bN[2];
    if (it < 15) ELOAD8(aN, bN, it + 1);   // prefetch next K-block
#pragma unroll
    for (int kk = 0; kk < 2; ++kk){
      short8 af[4], bfv[2];
#pragma unroll
      for (int m = 0; m < 4; ++m){
        const int r = wm + m * 16 + lr;
        af[m] = *(const short8*)(As + r * 128 + ((kk * 64 + lkb) ^ ((r & 7) << 4)));
      }
#pragma unroll
      for (int n = 0; n < 2; ++n){
        const int r = wn + n * 16 + lr;
        bfv[n] = *(const short8*)(Bs + r * 128 + ((kk * 64 + lkb) ^ ((r & 7) << 4)));
      }
#pragma unroll
      for (int m = 0; m < 4; ++m)
#pragma unroll
        for (int n = 0; n < 2; ++n)
          acc[m][n] = __builtin_amdgcn_mfma_f32_16x16x32_bf16(af[m], bfv[n], acc[m][n], 0, 0, 0);
    }
    if (it < 15){
      aR[0] = aN[0]; aR[1] = aN[1]; bR[0] = bN[0]; bR[1] = bN[1];
    }
  }
#undef ELOAD8

#pragma unroll
  for (int m = 0; m < 4; ++m)
#pragma unroll
    for (int n = 0; n < 2; ++n)
#pragma unroll
      for (int r = 0; r < 4; ++r){
        int gr = row0 + wm + m * 16 + lq + r;
        int gc = col0 + wn + n * 16 + lr;
        __hip_atomic_fetch_add(&Z[(long)gr * FOURH + gc], acc[m][n][r],
                               __ATOMIC_RELAXED, __HIP_MEMORY_SCOPE_AGENT);
      }
  __syncthreads();   // drains vmcnt: all atomics complete before counter bump
  if (tid == 0)
    __hip_atomic_fetch_add(&flags[CNT_BASE + bx * 32], 1u,
                           __ATOMIC_RELAXED, __HIP_MEMORY_SCOPE_AGENT);
}

// ---------------------------------------------------------------------------
// Decoder tile, 8-wave (512 thr), 128x128, K=300. Coherent stores (no bias),
// bumps per-bx counter (target 16).
// ---------------------------------------------------------------------------
__device__ __forceinline__ void dec_tile8(
    int bx, int by, const float* __restrict__ emb, const int* __restrict__ cap,
    const float* __restrict__ W, float* Z, char* smem, unsigned* flags)
{
  constexpr int KLIM  = D_WORD;
  constexpr int ITERS = (KLIM + 31) / 32;
  short* As = (short*)smem;              // [128][40]
  short* Bs = (short*)(smem + 10240);
  const int tid = threadIdx.x;
  const int row0 = bx * 128, col0 = by * 128;

  const int ar = tid >> 2, akq = (tid & 3) * 8;
  long asrc;
  {
    int R = row0 + ar;
    int b = R & 63, t = R >> 6;
    asrc = (long)cap[b * T_DEC + t] * D_WORD;
  }
  const int bc = tid & 127, bkq = (tid >> 7) * 8;

  const int wave = tid >> 6, lane = tid & 63;
  const int wm = (wave >> 2) * 64, wn = (wave & 3) * 32;
  const int lr = lane & 15, lk = (lane >> 4) << 3, lq = (lane >> 4) << 2;

  f32x4 acc[4][2];
#pragma unroll
  for (int m = 0; m < 4; ++m)
#pragma unroll
    for (int n = 0; n < 2; ++n) acc[m][n] = (f32x4){0.f, 0.f, 0.f, 0.f};

  for (int it = 0; it < ITERS; ++it){
    const int k0 = it * 32;
    float av[8], bv[8];
#pragma unroll
    for (int i = 0; i < 8; ++i){
      int k = k0 + akq + i;
      av[i] = (k < KLIM) ? emb[asrc + k] : 0.f;
    }
#pragma unroll
    for (int i = 0; i < 8; ++i){
      int k = k0 + bkq + i;
      bv[i] = (k < KLIM) ? W[(long)k * FOURH + col0 + bc] : 0.f;
    }
    __syncthreads();
    short8 a8, b8;
#pragma unroll
    for (int i = 0; i < 8; ++i){
      a8[i] = (short)f2bf(av[i]);  b8[i] = (short)f2bf(bv[i]);
    }
    *(short8*)&As[ar * 40 + akq] = a8;
    *(short8*)&Bs[bc * 40 + bkq] = b8;
    __syncthreads();
    short8 af[4], bfv[2];
#pragma unroll
    for (int m = 0; m < 4; ++m) af[m]  = *(const short8*)&As[(wm + m * 16 + lr) * 40 + lk];
#pragma unroll
    for (int n = 0; n < 2; ++n) bfv[n] = *(const short8*)&Bs[(wn + n * 16 + lr) * 40 + lk];
#pragma unroll
    for (int m = 0; m < 4; ++m)
#pragma unroll
      for (int n = 0; n < 2; ++n)
        acc[m][n] = __builtin_amdgcn_mfma_f32_16x16x32_bf16(af[m], bfv[n], acc[m][n], 0, 0, 0);
  }

#pragma unroll
  for (int m = 0; m < 4; ++m)
#pragma unroll
    for (int n = 0; n < 2; ++n)
#pragma unroll
      for (int r = 0; r < 4; ++r){
        int gr = row0 + wm + m * 16 + lq + r;
        int gc = col0 + wn + n * 16 + lr;
        __hip_atomic_store(&Z[(long)gr * FOURH + gc], acc[m][n][r],
                           __ATOMIC_RELAXED, __HIP_MEMORY_SCOPE_AGENT);
      }
  __syncthreads();
  if (tid == 0)
    __hip_atomic_fetch_add(&flags[CNT_BASE + (16 + bx) * 32], 1u,
                           __ATOMIC_RELAXED, __HIP_MEMORY_SCOPE_AGENT);
}

// ---------------------------------------------------------------------------
// Projection tail block: waits on dcnt[t] == 512 (one line, off the critical
// flag lines), then computes its 16 rows.
// ---------------------------------------------------------------------------
__device__ __forceinline__ void proj_tail(
    int p, const unsigned short* __restrict__ hsd, const float* __restrict__ Wp,
    const float* __restrict__ bp, float* __restrict__ out,
    unsigned* flags, char* smem)
{
  float* hl = (float*)smem;              // 16*512 f32 = 32 KB
  const int tid = threadIdx.x;
  const int r0 = p * 16;
  const int t  = r0 >> 6;                // all 16 rows same t

  {
    unsigned* dc = &flags[CNT_BASE + (26 + t) * 32];
    while (__hip_atomic_load(dc, __ATOMIC_RELAXED, __HIP_MEMORY_SCOPE_AGENT) < 512u)
      __builtin_amdgcn_s_sleep(16);
  }
  __builtin_amdgcn_sched_barrier(0);

  for (int idx = tid; idx < 16 * 512; idx += 512)
    hl[idx] = bf2f(hsd[(long)r0 * 512 + idx]);
  __syncthreads();
  if (tid < D_WORD){
    const int d = tid;
    float acc[16];
#pragma unroll
    for (int r = 0; r < 16; ++r) acc[r] = bp[d];
    for (int k = 0; k < 512; ++k){
      float w = Wp[k * D_WORD + d];
#pragma unroll
      for (int r = 0; r < 16; ++r) acc[r] += hl[r * 512 + k] * w;
    }
#pragma unroll
    for (int r = 0; r < 16; ++r){
      int R = r0 + r;
      int tt = R >> 6, b = R & 63;
      out[(long)(b * T_DEC + tt) * D_WORD + d] = acc[r];
    }
  }
}

// ---------------------------------------------------------------------------
// Fused kernel. LSTM blocks (bids 0..63) are now WAVE-AUTONOMOUS: each of the
// 8 waves owns 16 batches x (4 hid cols x 4 gates) with FULL K=512:
//   wave w: bg = w&3 (batches bg*16..+15), uh = w>>2 (hid cols uh*4..+3).
//   Lane c=lane&15: gate g=c>>2, hid u=uh*4+(c&3); i/j/f/o combined by an
//   in-wave shfl_xor(4/8) butterfly -> NO LDS, NO barriers in the step loop.
// Per-wave flags (128B lines); wave-level vmcnt drain before flag store.
// Protocol = R4-proven (tiny flag poll, bulk data read after observe).
// ---------------------------------------------------------------------------
__global__ __launch_bounds__(512, 4) void fused(
    const unsigned short* __restrict__ fbf, const unsigned short* __restrict__ wbf,
    float* Xe,
    const float* __restrict__ emb, const int* __restrict__ cap,
    const float* __restrict__ W_dec, float* Xd,
    const float* __restrict__ Wre, const float* __restrict__ Wrd,
    const float* __restrict__ b_enc, const float* __restrict__ b_dec,
    const float* __restrict__ Wp, const float* __restrict__ bp,
    float* __restrict__ out,
    unsigned* hbuf_u, unsigned* hsd_u, unsigned* flags)
{
  __shared__ __align__(16) char smem[32768];
  const int bid = blockIdx.x;

  if (bid >= 64){
    int g = bid - 64;
    if (g < 512)        enc_tile8(g >> 6, g & 15, (g >> 4) & 3, fbf, wbf, Xe, smem, flags);
    else if (g < 672){  int d = g - 512; dec_tile8(d >> 4, d & 15, emb, cap, W_dec, Xd, smem, flags); }
    else if (g < 1184){ int e = g - 672; enc_tile8(8 + (e >> 6), e & 15, (e >> 4) & 3, fbf, wbf, Xe, smem, flags); }
    else                proj_tail(g - 1184, (const unsigned short*)hsd_u, Wp, bp, out, flags, smem);
    return;
  }

  // ---------------- persistent LSTM block (8 autonomous waves) ----------------
  const int tid = threadIdx.x, wgid = bid;
  const int w = tid >> 6, lane = tid & 63;
  const int bg = w & 3, uh = w >> 2;
  const int c = lane & 15, hi4 = lane >> 4;
  const int g = c >> 2;                    // gate of this lane's MFMA column
  const int u = uh * 4 + (c & 3);          // hid col within wg (0..7)
  const int col4h = g * 512 + wgid * 8 + u;    // W/X column for this lane
  unsigned short* hb16 = (unsigned short*)hbuf_u;
  unsigned short* hs16 = (unsigned short*)hsd_u;

  // full-K weights: wv[ks] = B-frag (k = ks*32 + hi4*8 + j, col = col4h)
  short8 wv[16];
#pragma unroll
  for (int ks = 0; ks < 16; ++ks){
    short8 e;
#pragma unroll
    for (int j = 0; j < 8; ++j)
      e[j] = (short)f2bf(Wre[(long)(ks * 32 + hi4 * 8 + j) * FOURH + col4h]);
    wv[ks] = e;
  }
  const float be1 = b_enc[col4h], bd1 = b_dec[col4h];
  float c_reg[4] = {0.f, 0.f, 0.f, 0.f};

  const bool pub = (c < 4);                // 16 lanes publish (dedupe 4x gates)
  // init: publish h0 = 0 into buf0, then per-wave flag = 1
  if (pub){
#pragma unroll
    for (int r = 0; r < 4; ++r)
      __hip_atomic_store(&hb16[wgid * 512 + (bg * 16 + hi4 * 4 + r) * 8 + uh * 4 + c],
                         (unsigned short)0, __ATOMIC_RELAXED, __HIP_MEMORY_SCOPE_AGENT);
  }
  asm volatile("s_waitcnt vmcnt(0)" ::: "memory");
  if (lane == 0)
    __hip_atomic_store(&flags[(wgid * 8 + w) * 32], 1u,
                       __ATOMIC_RELAXED, __HIP_MEMORY_SCOPE_AGENT);

  const int obase = hi4 * 128 + (bg * 16 + c) * 2;   // ull idx of A-frag row

  for (int q = 0; q < T_ENC + T_DEC; ++q){
    const bool dec = (q >= T_ENC);
    const int tt = dec ? q - T_ENC : q;
    const float* Xp = dec ? Xd : Xe;

    if (q == T_ENC){   // one-time: swap recurrent weights enc -> dec in place
#pragma unroll
      for (int ks = 0; ks < 16; ++ks){
        short8 d;
#pragma unroll
        for (int j = 0; j < 8; ++j)
          d[j] = (short)f2bf(Wrd[(long)(ks * 32 + hi4 * 8 + j) * FOURH + col4h]);
        wv[ks] = d;
      }
    }

    // input-GEMM readiness (monotonic, covers 2 timesteps -> even tt only)
    if (!(tt & 1)){
      unsigned* xc = dec ? &flags[CNT_BASE + (16 + (tt >> 1)) * 32]
                         : &flags[CNT_BASE + (tt >> 1) * 32];
      const unsigned xtgt = dec ? 16u : 64u;
      while (__hip_atomic_load(xc, __ATOMIC_RELAXED, __HIP_MEMORY_SCOPE_AGENT) < xtgt)
        __builtin_amdgcn_s_sleep(2);
    }
    __builtin_amdgcn_sched_barrier(0);

    // x for this lane's gate/col, 4 batches (issued early; overlaps flag poll)
    float xg[4];
#pragma unroll
    for (int r = 0; r < 4; ++r)
      xg[r] = __hip_atomic_load(
          &Xp[(long)(tt * BATCH + bg * 16 + hi4 * 4 + r) * FOURH + col4h],
          __ATOMIC_RELAXED, __HIP_MEMORY_SCOPE_AGENT);

    // tiny flag poll: 2 words/lane (src waves {bg, bg+4} of wg = lane)
    {
      const unsigned tgt = (unsigned)(q + 1);
      for (;;){
        unsigned f0 = __hip_atomic_load(&flags[(lane * 8 + bg) * 32],
                                        __ATOMIC_RELAXED, __HIP_MEMORY_SCOPE_AGENT);
        unsigned f1 = __hip_atomic_load(&flags[(lane * 8 + bg + 4) * 32],
                                        __ATOMIC_RELAXED, __HIP_MEMORY_SCOPE_AGENT);
        if (__all((int)(f0 >= tgt && f1 >= tgt))) break;
        __builtin_amdgcn_s_sleep(1);
      }
    }
    __builtin_amdgcn_sched_barrier(0);

    // bulk h read + full-K MFMA chain (A row = lane&15 -> batch bg*16+c)
    const ull* rb = (const ull*)hbuf_u + (q & 1) * 8192;
    f32x4 acc = (f32x4){0.f, 0.f, 0.f, 0.f};
    __builtin_amdgcn_s_setprio(1);
#pragma unroll
    for (int ks = 0; ks < 16; ++ks){
      const int o = ks * 512 + obase;
      ull h0 = __hip_atomic_load(rb + o,     __ATOMIC_RELAXED, __HIP_MEMORY_SCOPE_AGENT);
      ull h1 = __hip_atomic_load(rb + o + 1, __ATOMIC_RELAXED, __HIP_MEMORY_SCOPE_AGENT);
      union { ull q2[2]; short8 s; } uf; uf.q2[0] = h0; uf.q2[1] = h1;
      acc = __builtin_amdgcn_mfma_f32_16x16x32_bf16(uf.s, wv[ks], acc, 0, 0, 0);
    }
    __builtin_amdgcn_s_setprio(0);

    // gate butterfly (in-wave) + elementwise; C row r -> batch bg*16+hi4*4+r
    unsigned short hbv[4];
#pragma unroll
    for (int r = 0; r < 4; ++r){
      float v = acc[r] + xg[r] + (dec ? bd1 : be1);
      float s4 = __shfl_xor(v, 4);
      float lo  = (g & 1) ? s4 : v;      // gate bit0 = 0  (i or f)
      float hi_ = (g & 1) ? v  : s4;     // gate bit0 = 1  (j or o)
      float lo8 = __shfl_xor(lo, 8);
      float hi8 = __shfl_xor(hi_, 8);
      float vzi = (g & 2) ? lo8 : lo;
      float vzf = (g & 2) ? lo  : lo8;
      float vzj = (g & 2) ? hi8 : hi_;
      float vzo = (g & 2) ? hi_ : hi8;
      c_reg[r] = c_reg[r] * sigm(vzf + 1.f) + sigm(vzi) * tanh_f(vzj);
      float hn = tanh_f(c_reg[r]) * sigm(vzo);
      hbv[r] = f2bf(hn);
    }

    // publish (16 lanes, 4 u16 each) + per-wave drain + per-wave flag
    if (pub){
#pragma unroll
      for (int r = 0; r < 4; ++r){
        const int b = bg * 16 + hi4 * 4 + r;
        __hip_atomic_store(&hb16[((q + 1) & 1) * 32768 + wgid * 512 + b * 8 + uh * 4 + c],
                           hbv[r], __ATOMIC_RELAXED, __HIP_MEMORY_SCOPE_AGENT);
        if (dec)
          __hip_atomic_store(&hs16[(long)(tt * BATCH + b) * 512 + wgid * 8 + uh * 4 + c],
                             hbv[r], __ATOMIC_RELAXED, __HIP_MEMORY_SCOPE_AGENT);
      }
    }
    asm volatile("s_waitcnt vmcnt(0)" ::: "memory");
    if (lane == 0)
      __hip_atomic_store(&flags[(wgid * 8 + w) * 32], (unsigned)(q + 2),
                         __ATOMIC_RELAXED, __HIP_MEMORY_SCOPE_AGENT);
    if (dec && lane == 1)
      __hip_atomic_fetch_add(&flags[CNT_BASE + (26 + tt) * 32], 1u,
                             __ATOMIC_RELAXED, __HIP_MEMORY_SCOPE_AGENT);
  }
}

// ---------------------------------------------------------------------------
extern "C" void kernel_launch(void* const* d_in, const int* in_sizes, int n_in,
                              void* d_out, int out_size, void* d_ws, size_t ws_size,
                              hipStream_t stream)
{
  const float* frames  = (const float*)d_in[0];
  const float* emb     = (const float*)d_in[1];
  const float* W_enc   = (const float*)d_in[2];
  const float* b_enc   = (const float*)d_in[3];
  const float* W_dec   = (const float*)d_in[4];
  const float* b_dec   = (const float*)d_in[5];
  const float* W_proj  = (const float*)d_in[6];
  const float* b_proj  = (const float*)d_in[7];
  const int*   caption = (const int*)d_in[8];

  char* ws = (char*)d_ws;
  float*          Xe    = (float*)(ws + 0);                 // 16 MB
  float*          Xd    = (float*)(ws + 16777216);          // 10 MB
  unsigned*       hbuf  = (unsigned*)(ws + 27262976);       // 128 KB (u16 x 2 buf)
  unsigned*       hsd   = (unsigned*)(ws + 27394048);       // 1.25 MB (u16)
  unsigned*       flags = (unsigned*)(ws + 28704768);       // 72 KB (wave flags + counters)
  unsigned short* fbf   = (unsigned short*)(ws + 28778496); // 16.78 MB (frames bf16)
  unsigned short* wbf   = (unsigned short*)(ws + 45555712); // 16.78 MB (W_enc^T bf16)
  float* out = (float*)d_out;

  prep<<<8192, 256, 0, stream>>>(frames, W_enc, fbf, wbf, flags, Xe);
  fused<<<64 + 1184 + 80, 512, 0, stream>>>(
      fbf, wbf, Xe, emb, caption, W_dec, Xd,
      W_enc + (long)D_IN * FOURH,
      W_dec + (long)D_WORD * FOURH,
      b_enc, b_dec, W_proj, b_proj, out,
      hbuf, hsd, flags);
}

// Round 7
// 485.684 us; speedup vs baseline: 1.5862x; 1.5862x over previous
//
#include <hip/hip_runtime.h>
#include <hip/hip_bf16.h>

#define BATCH  64
#define T_ENC  32
#define D_IN   4096
#define T_DEC  20
#define D_WORD 300
#define HID    512
#define FOURH  2048
#define NWG    64
#define FPAD   32   // flags stride in u32 (128B)  [R4-proven]
// flags layout (u32 idx): [wgid*FPAD] step flags (exclusive lines);
// [2048 + i*32] i=0..15 enc bx counters, i=16..25 dec bx counters,
// i=26..45 dcnt[t] (proj gating). Total 3520 u32.
#define CNT_BASE 2048
#define FLAGS_N  3520

typedef __attribute__((ext_vector_type(8))) short short8;
typedef __attribute__((ext_vector_type(4))) float f32x4;
typedef unsigned long long ull;

static __device__ __forceinline__ unsigned short f2bf(float f){
  union { float f; unsigned u; } v; v.f = f;
  unsigned r = v.u + 0x7fffu + ((v.u >> 16) & 1u);   // RNE
  return (unsigned short)(r >> 16);
}
static __device__ __forceinline__ float bf2f(unsigned short b){
  union { unsigned u; float f; } v; v.u = ((unsigned)b) << 16;
  return v.f;
}
static __device__ __forceinline__ float sigm(float x){
  return __builtin_amdgcn_rcpf(1.f + __expf(-x));
}
static __device__ __forceinline__ float tanh_f(float x){
  float e = __expf(2.f * x);
  return 1.f - 2.f * __builtin_amdgcn_rcpf(e + 1.f);
}

// ---------------------------------------------------------------------------
// prep: frames -> bf16, W_enc input rows -> bf16 transposed, zero flags
// (incl. GEMM counters + dcnt), zero Xe (fused accumulates via atomicAdd).
// [R4 verbatim]
// ---------------------------------------------------------------------------
__global__ __launch_bounds__(256) void prep(
    const float* __restrict__ frames, const float* __restrict__ W_enc,
    unsigned short* __restrict__ fb, unsigned short* __restrict__ wt,
    unsigned* __restrict__ flags, float* __restrict__ Xe)
{
  const int g = blockIdx.x * 256 + threadIdx.x;
  if (blockIdx.x == 0){
    for (int i = threadIdx.x; i < FLAGS_N; i += 256)
      __hip_atomic_store(&flags[i], 0u, __ATOMIC_RELAXED, __HIP_MEMORY_SCOPE_AGENT);
  }
  { // zero Xe: 4194304 floats, 2097152 threads -> float2 each
    float2 z2; z2.x = 0.f; z2.y = 0.f;
    *(float2*)(Xe + (long)g * 2) = z2;
  }
  if (g < 1048576){
    const long base = (long)g * 8;
    float4 x0 = *(const float4*)(frames + base);
    float4 x1 = *(const float4*)(frames + base + 4);
    short8 v;
    v[0] = (short)f2bf(x0.x); v[1] = (short)f2bf(x0.y);
    v[2] = (short)f2bf(x0.z); v[3] = (short)f2bf(x0.w);
    v[4] = (short)f2bf(x1.x); v[5] = (short)f2bf(x1.y);
    v[6] = (short)f2bf(x1.z); v[7] = (short)f2bf(x1.w);
    *(short8*)(fb + base) = v;
  } else {
    const int r  = g - 1048576;
    const int k0 = (r >> 11) << 3;       // 0..4088 step 8
    const int c  = r & 2047;             // coalesced reads across c
    short8 v;
#pragma unroll
    for (int j = 0; j < 8; ++j)
      v[j] = (short)f2bf(W_enc[(long)(k0 + j) * FOURH + c]);
    *(short8*)&wt[(long)c * D_IN + k0] = v;
  }
}

// ---------------------------------------------------------------------------
// Encoder tile, 8-wave (512 thr), 128x128, K-chunk = 1024 (BK=64, 16 iters),
// XOR-swizzled LDS, next-iter reg prefetch. Accumulates into Xe via fp32
// atomicAdd, bumps per-bx counter (target 64).  [R4 verbatim]
// ---------------------------------------------------------------------------
__device__ __forceinline__ void enc_tile8(
    int bx, int by, int kc,
    const unsigned short* __restrict__ A0, const unsigned short* __restrict__ Wt,
    float* Z, char* smem, unsigned* flags)
{
  char* As = smem;            // [128 rows][128B], byte ^= (row&7)<<4
  char* Bs = smem + 16384;
  const int tid = threadIdx.x;
  const int row0 = bx * 128, col0 = by * 128;

  const int ar = tid >> 2, ah = tid & 3;       // A: 4 thr/row, 16 shorts each
  long asrc;
  {
    int R = row0 + ar;
    int b = R & 63, t = R >> 6;
    asrc = (long)(b * T_ENC + t) * D_IN;
  }
  const int bc = tid & 127, bh = tid >> 7;     // B: 4 thr/col
  const long bsrc = (long)(col0 + bc) * D_IN;
  const long kbase = (long)kc * 1024;

  const int wave = tid >> 6, lane = tid & 63;
  const int wm = (wave >> 2) * 64, wn = (wave & 3) * 32;
  const int lr = lane & 15, lkb = (lane >> 4) << 4, lq = (lane >> 4) << 2;

  f32x4 acc[4][2];
#pragma unroll
  for (int m = 0; m < 4; ++m)
#pragma unroll
    for (int n = 0; n < 2; ++n) acc[m][n] = (f32x4){0.f, 0.f, 0.f, 0.f};

#define ELOAD8(DA, DB, IT) do { \
    const long ka = kbase + (long)(IT) * 64 + ah * 16; \
    const long kb = kbase + (long)(IT) * 64 + bh * 16; \
    _Pragma("unroll") \
    for (int j = 0; j < 2; ++j){ \
      DA[j] = *(const short8*)(A0 + asrc + ka + j * 8); \
      DB[j] = *(const short8*)(Wt + bsrc + kb + j * 8); \
    } \
  } while (0)

  short8 aR[2], bR[2];
  ELOAD8(aR, bR, 0);

  for (int it = 0; it < 16; ++it){
    __syncthreads();   // prev iter's frag reads done
#pragma unroll
    for (int j = 0; j < 2; ++j){
      *(short8*)(As + ar * 128 + ((ah * 32 + j * 16) ^ ((ar & 7) << 4))) = aR[j];
      *(short8*)(Bs + bc * 128 + ((bh * 32 + j * 16) ^ ((bc & 7) << 4))) = bR[j];
    }
    __syncthreads();
    short8 aN[2], bN[2];
    if (it < 15) ELOAD8(aN, bN, it + 1);   // prefetch next K-block
#pragma unroll
    for (int kk = 0; kk < 2; ++kk){
      short8 af[4], bfv[2];
#pragma unroll
      for (int m = 0; m < 4; ++m){
        const int r = wm + m * 16 + lr;
        af[m] = *(const short8*)(As + r * 128 + ((kk * 64 + lkb) ^ ((r & 7) << 4)));
      }
#pragma unroll
      for (int n = 0; n < 2; ++n){
        const int r = wn + n * 16 + lr;
        bfv[n] = *(const short8*)(Bs + r * 128 + ((kk * 64 + lkb) ^ ((r & 7) << 4)));
      }
#pragma unroll
      for (int m = 0; m < 4; ++m)
#pragma unroll
        for (int n = 0; n < 2; ++n)
          acc[m][n] = __builtin_amdgcn_mfma_f32_16x16x32_bf16(af[m], bfv[n], acc[m][n], 0, 0, 0);
    }
    if (it < 15){
      aR[0] = aN[0]; aR[1] = aN[1]; bR[0] = bN[0]; bR[1] = bN[1];
    }
  }
#undef ELOAD8

#pragma unroll
  for (int m = 0; m < 4; ++m)
#pragma unroll
    for (int n = 0; n < 2; ++n)
#pragma unroll
      for (int r = 0; r < 4; ++r){
        int gr = row0 + wm + m * 16 + lq + r;
        int gc = col0 + wn + n * 16 + lr;
        __hip_atomic_fetch_add(&Z[(long)gr * FOURH + gc], acc[m][n][r],
                               __ATOMIC_RELAXED, __HIP_MEMORY_SCOPE_AGENT);
      }
  __syncthreads();   // drains vmcnt: all atomics complete before counter bump
  if (tid == 0)
    __hip_atomic_fetch_add(&flags[CNT_BASE + bx * 32], 1u,
                           __ATOMIC_RELAXED, __HIP_MEMORY_SCOPE_AGENT);
}

// ---------------------------------------------------------------------------
// Decoder tile, 8-wave (512 thr), 128x128, K=300.  [R4 verbatim]
// ---------------------------------------------------------------------------
__device__ __forceinline__ void dec_tile8(
    int bx, int by, const float* __restrict__ emb, const int* __restrict__ cap,
    const float* __restrict__ W, float* Z, char* smem, unsigned* flags)
{
  constexpr int KLIM  = D_WORD;
  constexpr int ITERS = (KLIM + 31) / 32;
  short* As = (short*)smem;              // [128][40]
  short* Bs = (short*)(smem + 10240);
  const int tid = threadIdx.x;
  const int row0 = bx * 128, col0 = by * 128;

  const int ar = tid >> 2, akq = (tid & 3) * 8;
  long asrc;
  {
    int R = row0 + ar;
    int b = R & 63, t = R >> 6;
    asrc = (long)cap[b * T_DEC + t] * D_WORD;
  }
  const int bc = tid & 127, bkq = (tid >> 7) * 8;

  const int wave = tid >> 6, lane = tid & 63;
  const int wm = (wave >> 2) * 64, wn = (wave & 3) * 32;
  const int lr = lane & 15, lk = (lane >> 4) << 3, lq = (lane >> 4) << 2;

  f32x4 acc[4][2];
#pragma unroll
  for (int m = 0; m < 4; ++m)
#pragma unroll
    for (int n = 0; n < 2; ++n) acc[m][n] = (f32x4){0.f, 0.f, 0.f, 0.f};

  for (int it = 0; it < ITERS; ++it){
    const int k0 = it * 32;
    float av[8], bv[8];
#pragma unroll
    for (int i = 0; i < 8; ++i){
      int k = k0 + akq + i;
      av[i] = (k < KLIM) ? emb[asrc + k] : 0.f;
    }
#pragma unroll
    for (int i = 0; i < 8; ++i){
      int k = k0 + bkq + i;
      bv[i] = (k < KLIM) ? W[(long)k * FOURH + col0 + bc] : 0.f;
    }
    __syncthreads();
    short8 a8, b8;
#pragma unroll
    for (int i = 0; i < 8; ++i){
      a8[i] = (short)f2bf(av[i]);  b8[i] = (short)f2bf(bv[i]);
    }
    *(short8*)&As[ar * 40 + akq] = a8;
    *(short8*)&Bs[bc * 40 + bkq] = b8;
    __syncthreads();
    short8 af[4], bfv[2];
#pragma unroll
    for (int m = 0; m < 4; ++m) af[m]  = *(const short8*)&As[(wm + m * 16 + lr) * 40 + lk];
#pragma unroll
    for (int n = 0; n < 2; ++n) bfv[n] = *(const short8*)&Bs[(wn + n * 16 + lr) * 40 + lk];
#pragma unroll
    for (int m = 0; m < 4; ++m)
#pragma unroll
      for (int n = 0; n < 2; ++n)
        acc[m][n] = __builtin_amdgcn_mfma_f32_16x16x32_bf16(af[m], bfv[n], acc[m][n], 0, 0, 0);
  }

#pragma unroll
  for (int m = 0; m < 4; ++m)
#pragma unroll
    for (int n = 0; n < 2; ++n)
#pragma unroll
      for (int r = 0; r < 4; ++r){
        int gr = row0 + wm + m * 16 + lq + r;
        int gc = col0 + wn + n * 16 + lr;
        __hip_atomic_store(&Z[(long)gr * FOURH + gc], acc[m][n][r],
                           __ATOMIC_RELAXED, __HIP_MEMORY_SCOPE_AGENT);
      }
  __syncthreads();
  if (tid == 0)
    __hip_atomic_fetch_add(&flags[CNT_BASE + (16 + bx) * 32], 1u,
                           __ATOMIC_RELAXED, __HIP_MEMORY_SCOPE_AGENT);
}

// ---------------------------------------------------------------------------
// Projection tail block: waits on dcnt[t] == 64, then computes 16 rows.
// [R4 verbatim]
// ---------------------------------------------------------------------------
__device__ __forceinline__ void proj_tail(
    int p, const unsigned short* __restrict__ hsd, const float* __restrict__ Wp,
    const float* __restrict__ bp, float* __restrict__ out,
    unsigned* flags, char* smem)
{
  float* hl = (float*)smem;              // 16*512 f32 = 32 KB
  const int tid = threadIdx.x;
  const int r0 = p * 16;
  const int t  = r0 >> 6;                // all 16 rows same t

  {
    unsigned* dc = &flags[CNT_BASE + (26 + t) * 32];
    while (__hip_atomic_load(dc, __ATOMIC_RELAXED, __HIP_MEMORY_SCOPE_AGENT) < 64u)
      __builtin_amdgcn_s_sleep(16);
  }
  __builtin_amdgcn_sched_barrier(0);

  for (int idx = tid; idx < 16 * 512; idx += 512)
    hl[idx] = bf2f(hsd[(long)r0 * 512 + idx]);
  __syncthreads();
  if (tid < D_WORD){
    const int d = tid;
    float acc[16];
#pragma unroll
    for (int r = 0; r < 16; ++r) acc[r] = bp[d];
    for (int k = 0; k < 512; ++k){
      float w = Wp[k * D_WORD + d];
#pragma unroll
      for (int r = 0; r < 16; ++r) acc[r] += hl[r * 512 + k] * w;
    }
#pragma unroll
    for (int r = 0; r < 16; ++r){
      int R = r0 + r;
      int tt = R >> 6, b = R & 63;
      out[(long)(b * T_DEC + tt) * D_WORD + d] = acc[r];
    }
  }
}

// ---------------------------------------------------------------------------
// Fused kernel.  LSTM blocks: R4's block-level flag protocol + FULL-K waves
// (R6-verified math): wave w = (ch=w>>2)*4 + (mh=w&3) owns batches mh*16..+15
// x 16 cols (4 gates x 4 hid cols, u = ch*4 + c&3) with K=512 -> no zlds,
// no cross-wave reduce; gates combined by in-wave shfl_xor(4/8) butterfly.
// ONE barrier per step (vmcnt drain before flag store).  Dec weights reload
// in place at q==T_ENC (frees 64 VGPRs vs R4).  launch_bounds(512,1).
// ---------------------------------------------------------------------------
__global__ __launch_bounds__(512, 1) void fused(
    const unsigned short* __restrict__ fbf, const unsigned short* __restrict__ wbf,
    float* Xe,
    const float* __restrict__ emb, const int* __restrict__ cap,
    const float* __restrict__ W_dec, float* Xd,
    const float* __restrict__ Wre, const float* __restrict__ Wrd,
    const float* __restrict__ b_enc, const float* __restrict__ b_dec,
    const float* __restrict__ Wp, const float* __restrict__ bp,
    float* __restrict__ out,
    unsigned* hbuf_u, unsigned* hsd_u, unsigned* flags)
{
  __shared__ __align__(16) char smem[32768];
  const int bid = blockIdx.x;

  if (bid >= 64){
    int g = bid - 64;
    if (g < 512)        enc_tile8(g >> 6, g & 15, (g >> 4) & 3, fbf, wbf, Xe, smem, flags);
    else if (g < 672){  int d = g - 512; dec_tile8(d >> 4, d & 15, emb, cap, W_dec, Xd, smem, flags); }
    else if (g < 1184){ int e = g - 672; enc_tile8(8 + (e >> 6), e & 15, (e >> 4) & 3, fbf, wbf, Xe, smem, flags); }
    else                proj_tail(g - 1184, (const unsigned short*)hsd_u, Wp, bp, out, flags, smem);
    return;
  }

  // ---------------- persistent LSTM block (full-K waves) ----------------
  const int tid = threadIdx.x, wgid = bid;
  const int w = tid >> 6, lane = tid & 63;
  const int mh = w & 3, ch = w >> 2;           // batch group / col half
  const int c = lane & 15, hi4 = lane >> 4;
  const int g = c >> 2;                        // gate of this lane's column
  const int u = ch * 4 + (c & 3);              // hid col within wg (0..7)
  const int col4h = g * 512 + wgid * 8 + u;    // W/X column for this lane
  unsigned short* hb16 = (unsigned short*)hbuf_u;
  unsigned short* hs16 = (unsigned short*)hsd_u;

  // full-K weights: wv[ks] = B-frag (k = ks*32 + hi4*8 + j, col = col4h)
  short8 wv[16];
#pragma unroll
  for (int ks = 0; ks < 16; ++ks){
    short8 e;
#pragma unroll
    for (int j = 0; j < 8; ++j)
      e[j] = (short)f2bf(Wre[(long)(ks * 32 + hi4 * 8 + j) * FOURH + col4h]);
    wv[ks] = e;
  }
  const float be1 = b_enc[col4h], bd1 = b_dec[col4h];
  float c_reg[4] = {0.f, 0.f, 0.f, 0.f};

  // zero own slice of buffer 0 (wg-major: ull idx wgid*128 + 0..127)
  if (tid < 128)
    __hip_atomic_store((ull*)hbuf_u + wgid * 128 + tid, 0ull,
                       __ATOMIC_RELAXED, __HIP_MEMORY_SCOPE_AGENT);
  __syncthreads();
  if (tid == 0)
    __hip_atomic_store(&flags[wgid * FPAD], 1u,
                       __ATOMIC_RELAXED, __HIP_MEMORY_SCOPE_AGENT);

  const bool mine = (lane != wgid);
  const bool pub = (c < 4);                    // 16 lanes publish (dedupe gates)
  const int obase = hi4 * 128 + (mh * 16 + c) * 2;   // ull idx of A-frag row

  for (int q = 0; q < T_ENC + T_DEC; ++q){
    const bool dec = (q >= T_ENC);
    const int tt = dec ? q - T_ENC : q;
    const float* Xp = dec ? Xd : Xe;

    if (q == T_ENC){   // one-time: swap recurrent weights enc -> dec in place
#pragma unroll
      for (int ks = 0; ks < 16; ++ks){
        short8 d;
#pragma unroll
        for (int j = 0; j < 8; ++j)
          d[j] = (short)f2bf(Wrd[(long)(ks * 32 + hi4 * 8 + j) * FOURH + col4h]);
        wv[ks] = d;
      }
    }

    // input-GEMM readiness (monotonic, covers 2 timesteps -> even tt only)
    if (!(tt & 1)){
      unsigned* xc = dec ? &flags[CNT_BASE + (16 + (tt >> 1)) * 32]
                         : &flags[CNT_BASE + (tt >> 1) * 32];
      const unsigned xtgt = dec ? 16u : 64u;
      while (__hip_atomic_load(xc, __ATOMIC_RELAXED, __HIP_MEMORY_SCOPE_AGENT) < xtgt)
        __builtin_amdgcn_s_sleep(2);
    }
    __builtin_amdgcn_sched_barrier(0);

    // x for this lane's (batch rows, col), issued before the flag poll
    float xg[4];
#pragma unroll
    for (int r = 0; r < 4; ++r)
      xg[r] = __hip_atomic_load(
          &Xp[(long)(tt * BATCH + mh * 16 + hi4 * 4 + r) * FOURH + col4h],
          __ATOMIC_RELAXED, __HIP_MEMORY_SCOPE_AGENT);

    // tiny flag poll: 1 word/lane (R4-proven)
    {
      const unsigned tgt = (unsigned)(q + 1);
      for (;;){
        unsigned f = tgt;
        if (mine) f = __hip_atomic_load(&flags[lane * FPAD],
                                        __ATOMIC_RELAXED, __HIP_MEMORY_SCOPE_AGENT);
        if (__all((int)(f >= tgt))) break;
        __builtin_amdgcn_s_sleep(1);
      }
    }
    __builtin_amdgcn_sched_barrier(0);

    // bulk h read + full-K MFMA chain (A row = batch mh*16+c)
    const ull* rb = (const ull*)hbuf_u + (q & 1) * 8192;
    f32x4 acc = (f32x4){0.f, 0.f, 0.f, 0.f};
    __builtin_amdgcn_s_setprio(1);
#pragma unroll
    for (int ks = 0; ks < 16; ++ks){
      const int o = ks * 512 + obase;
      ull h0 = __hip_atomic_load(rb + o,     __ATOMIC_RELAXED, __HIP_MEMORY_SCOPE_AGENT);
      ull h1 = __hip_atomic_load(rb + o + 1, __ATOMIC_RELAXED, __HIP_MEMORY_SCOPE_AGENT);
      union { ull q2[2]; short8 s; } uf; uf.q2[0] = h0; uf.q2[1] = h1;
      acc = __builtin_amdgcn_mfma_f32_16x16x32_bf16(uf.s, wv[ks], acc, 0, 0, 0);
    }
    __builtin_amdgcn_s_setprio(0);

    // gate butterfly (in-wave, R6-verified) + elementwise
    unsigned short hbv[4];
#pragma unroll
    for (int r = 0; r < 4; ++r){
      float v = acc[r] + xg[r] + (dec ? bd1 : be1);
      float s4 = __shfl_xor(v, 4);
      float lo  = (g & 1) ? s4 : v;      // i or f
      float hi_ = (g & 1) ? v  : s4;     // j or o
      float lo8 = __shfl_xor(lo, 8);
      float hi8 = __shfl_xor(hi_, 8);
      float vzi = (g & 2) ? lo8 : lo;
      float vzf = (g & 2) ? lo  : lo8;
      float vzj = (g & 2) ? hi8 : hi_;
      float vzo = (g & 2) ? hi_ : hi8;
      c_reg[r] = c_reg[r] * sigm(vzf + 1.f) + sigm(vzi) * tanh_f(vzj);
      float hn = tanh_f(c_reg[r]) * sigm(vzo);
      hbv[r] = f2bf(hn);
    }

    // publish (16 lanes/wave, 4 u16 each -> wg's 1KB slice)
    if (pub){
#pragma unroll
      for (int r = 0; r < 4; ++r){
        const int b = mh * 16 + hi4 * 4 + r;
        __hip_atomic_store(&hb16[((q + 1) & 1) * 32768 + wgid * 512 + b * 8 + u],
                           hbv[r], __ATOMIC_RELAXED, __HIP_MEMORY_SCOPE_AGENT);
        if (dec)
          __hip_atomic_store(&hs16[(long)(tt * BATCH + b) * 512 + wgid * 8 + u],
                             hbv[r], __ATOMIC_RELAXED, __HIP_MEMORY_SCOPE_AGENT);
      }
    }

    __syncthreads();   // drains vmcnt: h/hsd stores visible before flag/dcnt
    if (tid == 0)
      __hip_atomic_store(&flags[wgid * FPAD], (unsigned)(q + 2),
                         __ATOMIC_RELAXED, __HIP_MEMORY_SCOPE_AGENT);
    if (dec && tid == 64)
      __hip_atomic_fetch_add(&flags[CNT_BASE + (26 + tt) * 32], 1u,
                             __ATOMIC_RELAXED, __HIP_MEMORY_SCOPE_AGENT);
  }
}

// ---------------------------------------------------------------------------
extern "C" void kernel_launch(void* const* d_in, const int* in_sizes, int n_in,
                              void* d_out, int out_size, void* d_ws, size_t ws_size,
                              hipStream_t stream)
{
  const float* frames  = (const float*)d_in[0];
  const float* emb     = (const float*)d_in[1];
  const float* W_enc   = (const float*)d_in[2];
  const float* b_enc   = (const float*)d_in[3];
  const float* W_dec   = (const float*)d_in[4];
  const float* b_dec   = (const float*)d_in[5];
  const float* W_proj  = (const float*)d_in[6];
  const float* b_proj  = (const float*)d_in[7];
  const int*   caption = (const int*)d_in[8];

  char* ws = (char*)d_ws;
  float*          Xe    = (float*)(ws + 0);                 // 16 MB
  float*          Xd    = (float*)(ws + 16777216);          // 10 MB
  unsigned*       hbuf  = (unsigned*)(ws + 27262976);       // 128 KB (u16 x 2 buf)
  unsigned*       hsd   = (unsigned*)(ws + 27394048);       // 1.25 MB (u16)
  unsigned*       flags = (unsigned*)(ws + 28704768);       // 16 KB (flags+counters+dcnt)
  unsigned short* fbf   = (unsigned short*)(ws + 28721152); // 16.78 MB (frames bf16)
  unsigned short* wbf   = (unsigned short*)(ws + 45498368); // 16.78 MB (W_enc^T bf16)
  float* out = (float*)d_out;

  prep<<<8192, 256, 0, stream>>>(frames, W_enc, fbf, wbf, flags, Xe);
  fused<<<64 + 1184 + 80, 512, 0, stream>>>(
      fbf, wbf, Xe, emb, caption, W_dec, Xd,
      W_enc + (long)D_IN * FOURH,
      W_dec + (long)D_WORD * FOURH,
      b_enc, b_dec, W_proj, b_proj, out,
      hbuf, hsd, flags);
}

// Round 8
// 366.772 us; speedup vs baseline: 2.1004x; 1.3242x over previous
//
#include <hip/hip_runtime.h>
#include <hip/hip_bf16.h>

#define BATCH  64
#define T_ENC  32
#define D_IN   4096
#define T_DEC  20
#define D_WORD 300
#define HID    512
#define FOURH  2048
#define NWG    64
#define FPAD   32   // flags stride in u32 (128B)  [R4-proven]
// flags layout (u32 idx): [wgid*FPAD] step flags (exclusive lines);
// [2048 + i*32] i=0..15 enc bx counters, i=16..25 dec bx counters,
// i=26..45 dcnt[t] (proj gating). Total 3520 u32.
#define CNT_BASE 2048
#define FLAGS_N  3520

typedef __attribute__((ext_vector_type(8))) short short8;
typedef __attribute__((ext_vector_type(4))) float f32x4;
typedef unsigned long long ull;

static __device__ __forceinline__ unsigned short f2bf(float f){
  union { float f; unsigned u; } v; v.f = f;
  unsigned r = v.u + 0x7fffu + ((v.u >> 16) & 1u);   // RNE
  return (unsigned short)(r >> 16);
}
static __device__ __forceinline__ float bf2f(unsigned short b){
  union { unsigned u; float f; } v; v.u = ((unsigned)b) << 16;
  return v.f;
}
static __device__ __forceinline__ float sigm(float x){
  return __builtin_amdgcn_rcpf(1.f + __expf(-x));
}
static __device__ __forceinline__ float tanh_f(float x){
  float e = __expf(2.f * x);
  return 1.f - 2.f * __builtin_amdgcn_rcpf(e + 1.f);
}

// ---------------------------------------------------------------------------
// prep: frames -> bf16, W_enc input rows -> bf16 transposed, zero flags
// (incl. GEMM counters + dcnt), zero Xe (fused accumulates via atomicAdd).
// [R4 verbatim]
// ---------------------------------------------------------------------------
__global__ __launch_bounds__(256) void prep(
    const float* __restrict__ frames, const float* __restrict__ W_enc,
    unsigned short* __restrict__ fb, unsigned short* __restrict__ wt,
    unsigned* __restrict__ flags, float* __restrict__ Xe)
{
  const int g = blockIdx.x * 256 + threadIdx.x;
  if (blockIdx.x == 0){
    for (int i = threadIdx.x; i < FLAGS_N; i += 256)
      __hip_atomic_store(&flags[i], 0u, __ATOMIC_RELAXED, __HIP_MEMORY_SCOPE_AGENT);
  }
  { // zero Xe: 4194304 floats, 2097152 threads -> float2 each
    float2 z2; z2.x = 0.f; z2.y = 0.f;
    *(float2*)(Xe + (long)g * 2) = z2;
  }
  if (g < 1048576){
    const long base = (long)g * 8;
    float4 x0 = *(const float4*)(frames + base);
    float4 x1 = *(const float4*)(frames + base + 4);
    short8 v;
    v[0] = (short)f2bf(x0.x); v[1] = (short)f2bf(x0.y);
    v[2] = (short)f2bf(x0.z); v[3] = (short)f2bf(x0.w);
    v[4] = (short)f2bf(x1.x); v[5] = (short)f2bf(x1.y);
    v[6] = (short)f2bf(x1.z); v[7] = (short)f2bf(x1.w);
    *(short8*)(fb + base) = v;
  } else {
    const int r  = g - 1048576;
    const int k0 = (r >> 11) << 3;       // 0..4088 step 8
    const int c  = r & 2047;             // coalesced reads across c
    short8 v;
#pragma unroll
    for (int j = 0; j < 8; ++j)
      v[j] = (short)f2bf(W_enc[(long)(k0 + j) * FOURH + c]);
    *(short8*)&wt[(long)c * D_IN + k0] = v;
  }
}

// ---------------------------------------------------------------------------
// Encoder tile, 8-wave (512 thr), 128x128, K-chunk = 1024 (BK=64, 16 iters),
// XOR-swizzled LDS, next-iter reg prefetch. Accumulates into Xe via fp32
// atomicAdd, bumps per-bx counter (target 64).  [R4 verbatim]
// ---------------------------------------------------------------------------
__device__ __forceinline__ void enc_tile8(
    int bx, int by, int kc,
    const unsigned short* __restrict__ A0, const unsigned short* __restrict__ Wt,
    float* Z, char* smem, unsigned* flags)
{
  char* As = smem;            // [128 rows][128B], byte ^= (row&7)<<4
  char* Bs = smem + 16384;
  const int tid = threadIdx.x;
  const int row0 = bx * 128, col0 = by * 128;

  const int ar = tid >> 2, ah = tid & 3;       // A: 4 thr/row, 16 shorts each
  long asrc;
  {
    int R = row0 + ar;
    int b = R & 63, t = R >> 6;
    asrc = (long)(b * T_ENC + t) * D_IN;
  }
  const int bc = tid & 127, bh = tid >> 7;     // B: 4 thr/col
  const long bsrc = (long)(col0 + bc) * D_IN;
  const long kbase = (long)kc * 1024;

  const int wave = tid >> 6, lane = tid & 63;
  const int wm = (wave >> 2) * 64, wn = (wave & 3) * 32;
  const int lr = lane & 15, lkb = (lane >> 4) << 4, lq = (lane >> 4) << 2;

  f32x4 acc[4][2];
#pragma unroll
  for (int m = 0; m < 4; ++m)
#pragma unroll
    for (int n = 0; n < 2; ++n) acc[m][n] = (f32x4){0.f, 0.f, 0.f, 0.f};

#define ELOAD8(DA, DB, IT) do { \
    const long ka = kbase + (long)(IT) * 64 + ah * 16; \
    const long kb = kbase + (long)(IT) * 64 + bh * 16; \
    _Pragma("unroll") \
    for (int j = 0; j < 2; ++j){ \
      DA[j] = *(const short8*)(A0 + asrc + ka + j * 8); \
      DB[j] = *(const short8*)(Wt + bsrc + kb + j * 8); \
    } \
  } while (0)

  short8 aR[2], bR[2];
  ELOAD8(aR, bR, 0);

  for (int it = 0; it < 16; ++it){
    __syncthreads();   // prev iter's frag reads done
#pragma unroll
    for (int j = 0; j < 2; ++j){
      *(short8*)(As + ar * 128 + ((ah * 32 + j * 16) ^ ((ar & 7) << 4))) = aR[j];
      *(short8*)(Bs + bc * 128 + ((bh * 32 + j * 16) ^ ((bc & 7) << 4))) = bR[j];
    }
    __syncthreads();
    short8 aN[2], bN[2];
    if (it < 15) ELOAD8(aN, bN, it + 1);   // prefetch next K-block
#pragma unroll
    for (int kk = 0; kk < 2; ++kk){
      short8 af[4], bfv[2];
#pragma unroll
      for (int m = 0; m < 4; ++m){
        const int r = wm + m * 16 + lr;
        af[m] = *(const short8*)(As + r * 128 + ((kk * 64 + lkb) ^ ((r & 7) << 4)));
      }
#pragma unroll
      for (int n = 0; n < 2; ++n){
        const int r = wn + n * 16 + lr;
        bfv[n] = *(const short8*)(Bs + r * 128 + ((kk * 64 + lkb) ^ ((r & 7) << 4)));
      }
#pragma unroll
      for (int m = 0; m < 4; ++m)
#pragma unroll
        for (int n = 0; n < 2; ++n)
          acc[m][n] = __builtin_amdgcn_mfma_f32_16x16x32_bf16(af[m], bfv[n], acc[m][n], 0, 0, 0);
    }
    if (it < 15){
      aR[0] = aN[0]; aR[1] = aN[1]; bR[0] = bN[0]; bR[1] = bN[1];
    }
  }
#undef ELOAD8

#pragma unroll
  for (int m = 0; m < 4; ++m)
#pragma unroll
    for (int n = 0; n < 2; ++n)
#pragma unroll
      for (int r = 0; r < 4; ++r){
        int gr = row0 + wm + m * 16 + lq + r;
        int gc = col0 + wn + n * 16 + lr;
        __hip_atomic_fetch_add(&Z[(long)gr * FOURH + gc], acc[m][n][r],
                               __ATOMIC_RELAXED, __HIP_MEMORY_SCOPE_AGENT);
      }
  __syncthreads();   // drains vmcnt: all atomics complete before counter bump
  if (tid == 0)
    __hip_atomic_fetch_add(&flags[CNT_BASE + bx * 32], 1u,
                           __ATOMIC_RELAXED, __HIP_MEMORY_SCOPE_AGENT);
}

// ---------------------------------------------------------------------------
// Decoder tile, 8-wave (512 thr), 128x128, K=300.  [R4 verbatim]
// ---------------------------------------------------------------------------
__device__ __forceinline__ void dec_tile8(
    int bx, int by, const float* __restrict__ emb, const int* __restrict__ cap,
    const float* __restrict__ W, float* Z, char* smem, unsigned* flags)
{
  constexpr int KLIM  = D_WORD;
  constexpr int ITERS = (KLIM + 31) / 32;
  short* As = (short*)smem;              // [128][40]
  short* Bs = (short*)(smem + 10240);
  const int tid = threadIdx.x;
  const int row0 = bx * 128, col0 = by * 128;

  const int ar = tid >> 2, akq = (tid & 3) * 8;
  long asrc;
  {
    int R = row0 + ar;
    int b = R & 63, t = R >> 6;
    asrc = (long)cap[b * T_DEC + t] * D_WORD;
  }
  const int bc = tid & 127, bkq = (tid >> 7) * 8;

  const int wave = tid >> 6, lane = tid & 63;
  const int wm = (wave >> 2) * 64, wn = (wave & 3) * 32;
  const int lr = lane & 15, lk = (lane >> 4) << 3, lq = (lane >> 4) << 2;

  f32x4 acc[4][2];
#pragma unroll
  for (int m = 0; m < 4; ++m)
#pragma unroll
    for (int n = 0; n < 2; ++n) acc[m][n] = (f32x4){0.f, 0.f, 0.f, 0.f};

  for (int it = 0; it < ITERS; ++it){
    const int k0 = it * 32;
    float av[8], bv[8];
#pragma unroll
    for (int i = 0; i < 8; ++i){
      int k = k0 + akq + i;
      av[i] = (k < KLIM) ? emb[asrc + k] : 0.f;
    }
#pragma unroll
    for (int i = 0; i < 8; ++i){
      int k = k0 + bkq + i;
      bv[i] = (k < KLIM) ? W[(long)k * FOURH + col0 + bc] : 0.f;
    }
    __syncthreads();
    short8 a8, b8;
#pragma unroll
    for (int i = 0; i < 8; ++i){
      a8[i] = (short)f2bf(av[i]);  b8[i] = (short)f2bf(bv[i]);
    }
    *(short8*)&As[ar * 40 + akq] = a8;
    *(short8*)&Bs[bc * 40 + bkq] = b8;
    __syncthreads();
    short8 af[4], bfv[2];
#pragma unroll
    for (int m = 0; m < 4; ++m) af[m]  = *(const short8*)&As[(wm + m * 16 + lr) * 40 + lk];
#pragma unroll
    for (int n = 0; n < 2; ++n) bfv[n] = *(const short8*)&Bs[(wn + n * 16 + lr) * 40 + lk];
#pragma unroll
    for (int m = 0; m < 4; ++m)
#pragma unroll
      for (int n = 0; n < 2; ++n)
        acc[m][n] = __builtin_amdgcn_mfma_f32_16x16x32_bf16(af[m], bfv[n], acc[m][n], 0, 0, 0);
  }

#pragma unroll
  for (int m = 0; m < 4; ++m)
#pragma unroll
    for (int n = 0; n < 2; ++n)
#pragma unroll
      for (int r = 0; r < 4; ++r){
        int gr = row0 + wm + m * 16 + lq + r;
        int gc = col0 + wn + n * 16 + lr;
        __hip_atomic_store(&Z[(long)gr * FOURH + gc], acc[m][n][r],
                           __ATOMIC_RELAXED, __HIP_MEMORY_SCOPE_AGENT);
      }
  __syncthreads();
  if (tid == 0)
    __hip_atomic_fetch_add(&flags[CNT_BASE + (16 + bx) * 32], 1u,
                           __ATOMIC_RELAXED, __HIP_MEMORY_SCOPE_AGENT);
}

// ---------------------------------------------------------------------------
// Projection tail block: waits on dcnt[t] == 64, then computes 16 rows.
// [R4 verbatim]
// ---------------------------------------------------------------------------
__device__ __forceinline__ void proj_tail(
    int p, const unsigned short* __restrict__ hsd, const float* __restrict__ Wp,
    const float* __restrict__ bp, float* __restrict__ out,
    unsigned* flags, char* smem)
{
  float* hl = (float*)smem;              // 16*512 f32 = 32 KB
  const int tid = threadIdx.x;
  const int r0 = p * 16;
  const int t  = r0 >> 6;                // all 16 rows same t

  {
    unsigned* dc = &flags[CNT_BASE + (26 + t) * 32];
    while (__hip_atomic_load(dc, __ATOMIC_RELAXED, __HIP_MEMORY_SCOPE_AGENT) < 64u)
      __builtin_amdgcn_s_sleep(16);
  }
  __builtin_amdgcn_sched_barrier(0);

  for (int idx = tid; idx < 16 * 512; idx += 512)
    hl[idx] = bf2f(hsd[(long)r0 * 512 + idx]);
  __syncthreads();
  if (tid < D_WORD){
    const int d = tid;
    float acc[16];
#pragma unroll
    for (int r = 0; r < 16; ++r) acc[r] = bp[d];
    for (int k = 0; k < 512; ++k){
      float w = Wp[k * D_WORD + d];
#pragma unroll
      for (int r = 0; r < 16; ++r) acc[r] += hl[r * 512 + k] * w;
    }
#pragma unroll
    for (int r = 0; r < 16; ++r){
      int R = r0 + r;
      int tt = R >> 6, b = R & 63;
      out[(long)(b * T_DEC + tt) * D_WORD + d] = acc[r];
    }
  }
}

// ---------------------------------------------------------------------------
// Persistent LSTM: BATCH-GROUP-LOCAL sync (R8).  wg = (bg = wg>>4, cs = wg&15)
// owns 16 batches (bg*16..+15) x 32 HID cols (cs*32..+31).  The 4 bg chains
// are fully independent; each wg polls only the 16 flags of its own group.
// Per-wave micro-structure is R4-VERBATIM: wave (kh = K-half, ch = gate),
// ha[16] bulk h read (hoistable), 2 independent 8-deep MFMA chains, zlds
// 2-barrier K-reduce, all-thread contiguous u16 publish.
// hbuf layout: [buf][b_global 0..63][k 0..511] u16 (row-major per batch).
// ---------------------------------------------------------------------------
#define REC_GEMM(WREG) do { \
  _Pragma("unroll") \
  for (int ks = 0; ks < 8; ++ks){ \
    short8 af; \
    ((ull*)&af)[0] = ha[2 * ks]; \
    ((ull*)&af)[1] = ha[2 * ks + 1]; \
    _Pragma("unroll") \
    for (int n = 0; n < 2; ++n) \
      acc[n] = __builtin_amdgcn_mfma_f32_16x16x32_bf16(af, WREG[ks][n], acc[n], 0, 0, 0); \
  } \
} while (0)

// ---------------------------------------------------------------------------
// Fused kernel: bids 0..63 = persistent LSTM; 64..1247 = input-GEMM tiles
// (enc bx0..7, then dec, then enc bx8..15); 1248..1327 = projection tails.
// ---------------------------------------------------------------------------
__global__ __launch_bounds__(512, 1) void fused(
    const unsigned short* __restrict__ fbf, const unsigned short* __restrict__ wbf,
    float* Xe,
    const float* __restrict__ emb, const int* __restrict__ cap,
    const float* __restrict__ W_dec, float* Xd,
    const float* __restrict__ Wre, const float* __restrict__ Wrd,
    const float* __restrict__ b_enc, const float* __restrict__ b_dec,
    const float* __restrict__ Wp, const float* __restrict__ bp,
    float* __restrict__ out,
    unsigned* hbuf_u, unsigned* hsd_u, unsigned* flags)
{
  __shared__ __align__(16) char smem[32768];
  const int bid = blockIdx.x;

  if (bid >= 64){
    int g = bid - 64;
    if (g < 512)        enc_tile8(g >> 6, g & 15, (g >> 4) & 3, fbf, wbf, Xe, smem, flags);
    else if (g < 672){  int d = g - 512; dec_tile8(d >> 4, d & 15, emb, cap, W_dec, Xd, smem, flags); }
    else if (g < 1184){ int e = g - 672; enc_tile8(8 + (e >> 6), e & 15, (e >> 4) & 3, fbf, wbf, Xe, smem, flags); }
    else                proj_tail(g - 1184, (const unsigned short*)hsd_u, Wp, bp, out, flags, smem);
    return;
  }

  // ---------------- persistent LSTM block (bg-local group) ----------------
  float* zlds = (float*)smem;              // 8 x 32 rows x 17 f32 = 17.4 KB
  const int tid = threadIdx.x, wgid = bid;
  const int bg = wgid >> 4, cs = wgid & 15;
  const int w = tid >> 6, lane = tid & 63;
  const int kh = w >> 2, ch = w & 3;           // K-half (0..1) / gate (0..3)
  const int lr = lane & 15, hi4 = lane >> 4, lq = hi4 * 4;
  unsigned short* hb16 = (unsigned short*)hbuf_u;
  unsigned short* hs16 = (unsigned short*)hsd_u;

  int ocol[2];
#pragma unroll
  for (int n = 0; n < 2; ++n)
    ocol[n] = ch * 512 + cs * 32 + n * 16 + lr;   // this wave's gate=ch cols

  // recurrent weights, both phases resident (R4-proven budget)
  short8 we[8][2], wd[8][2];
#pragma unroll
  for (int ks = 0; ks < 8; ++ks)
#pragma unroll
    for (int n = 0; n < 2; ++n){
      short8 e, d;
#pragma unroll
      for (int j = 0; j < 8; ++j){
        int k = kh * 256 + ks * 32 + hi4 * 8 + j;
        e[j] = (short)f2bf(Wre[(long)k * FOURH + ocol[n]]);
        d[j] = (short)f2bf(Wrd[(long)k * FOURH + ocol[n]]);
      }
      we[ks][n] = e; wd[ks][n] = d;
    }

  const int b_ = tid >> 5, u_ = tid & 31;      // elementwise: batch, hid col
  float c_reg = 0.f;

  float be4[4], bd4[4];
#pragma unroll
  for (int gg = 0; gg < 4; ++gg){
    be4[gg] = b_enc[gg * 512 + cs * 32 + u_];
    bd4[gg] = b_dec[gg * 512 + cs * 32 + u_];
  }

  // zero own slice of buffer 0: 16 b x 32 cols = 128 ulls
  if (tid < 128)
    __hip_atomic_store((ull*)hbuf_u + (bg * 16 + (tid >> 3)) * 128 + cs * 8 + (tid & 7),
                       0ull, __ATOMIC_RELAXED, __HIP_MEMORY_SCOPE_AGENT);
  __syncthreads();
  if (tid == 0)
    __hip_atomic_store(&flags[wgid * FPAD], 1u,
                       __ATOMIC_RELAXED, __HIP_MEMORY_SCOPE_AGENT);

  const int fsrc = (bg * 16 + (lane & 15)) * FPAD;   // group flag (4 lanes each)
  const int obase = (bg * 16 + lr) * 128 + kh * 64 + hi4 * 2;  // ull A-frag base

  for (int q = 0; q < T_ENC + T_DEC; ++q){
    const bool dec = (q >= T_ENC);
    const int tt = dec ? q - T_ENC : q;
    const float* Xp = dec ? Xd : Xe;

    // input-GEMM readiness (monotonic, covers 2 timesteps -> even tt only)
    if (!(tt & 1)){
      unsigned* xc = dec ? &flags[CNT_BASE + (16 + (tt >> 1)) * 32]
                         : &flags[CNT_BASE + (tt >> 1) * 32];
      const unsigned xtgt = dec ? 16u : 64u;
      while (__hip_atomic_load(xc, __ATOMIC_RELAXED, __HIP_MEMORY_SCOPE_AGENT) < xtgt)
        __builtin_amdgcn_s_sleep(2);
    }
    __builtin_amdgcn_sched_barrier(0);

    // x for this thread's (batch, col), issued before the flag poll
    const long xb = (long)(tt * BATCH + bg * 16 + b_) * FOURH + cs * 32 + u_;
    float xi = __hip_atomic_load(&Xp[xb],        __ATOMIC_RELAXED, __HIP_MEMORY_SCOPE_AGENT);
    float xj = __hip_atomic_load(&Xp[xb +  512], __ATOMIC_RELAXED, __HIP_MEMORY_SCOPE_AGENT);
    float xf = __hip_atomic_load(&Xp[xb + 1024], __ATOMIC_RELAXED, __HIP_MEMORY_SCOPE_AGENT);
    float xo = __hip_atomic_load(&Xp[xb + 1536], __ATOMIC_RELAXED, __HIP_MEMORY_SCOPE_AGENT);

    // tiny flag poll: GROUP-LOCAL, 16 flags (4 lanes per flag)
    {
      const unsigned tgt = (unsigned)(q + 1);
      for (;;){
        unsigned f = __hip_atomic_load(&flags[fsrc],
                                       __ATOMIC_RELAXED, __HIP_MEMORY_SCOPE_AGENT);
        if (__all((int)(f >= tgt))) break;
        __builtin_amdgcn_s_sleep(1);
      }
    }
    __builtin_amdgcn_sched_barrier(0);

    // bulk h read: 16x8B (R4-proven hoistable shape)
    const ull* rb = (const ull*)hbuf_u + (q & 1) * 8192;
    ull ha[16];
#pragma unroll
    for (int ks = 0; ks < 8; ++ks){
      const int o = obase + ks * 8;
      ha[2 * ks]     = __hip_atomic_load(rb + o,     __ATOMIC_RELAXED, __HIP_MEMORY_SCOPE_AGENT);
      ha[2 * ks + 1] = __hip_atomic_load(rb + o + 1, __ATOMIC_RELAXED, __HIP_MEMORY_SCOPE_AGENT);
    }

    f32x4 acc[2];
#pragma unroll
    for (int n = 0; n < 2; ++n) acc[n] = (f32x4){0.f, 0.f, 0.f, 0.f};
    __builtin_amdgcn_s_setprio(1);
    if (!dec) REC_GEMM(we); else REC_GEMM(wd);
    __builtin_amdgcn_s_setprio(0);

    // zlds K-reduce: row = (kh*4+ch)*32 + (n*16+lr), entry = batch (lq+r)
#pragma unroll
    for (int n = 0; n < 2; ++n)
#pragma unroll
      for (int r = 0; r < 4; ++r)
        zlds[((kh * 4 + ch) * 32 + n * 16 + lr) * 17 + lq + r] = acc[n][r];
    __syncthreads();

    float zi = zlds[((0 * 4 + 0) * 32 + u_) * 17 + b_] + zlds[((1 * 4 + 0) * 32 + u_) * 17 + b_] + xi + (dec ? bd4[0] : be4[0]);
    float zj = zlds[((0 * 4 + 1) * 32 + u_) * 17 + b_] + zlds[((1 * 4 + 1) * 32 + u_) * 17 + b_] + xj + (dec ? bd4[1] : be4[1]);
    float zf = zlds[((0 * 4 + 2) * 32 + u_) * 17 + b_] + zlds[((1 * 4 + 2) * 32 + u_) * 17 + b_] + xf + (dec ? bd4[2] : be4[2]);
    float zo = zlds[((0 * 4 + 3) * 32 + u_) * 17 + b_] + zlds[((1 * 4 + 3) * 32 + u_) * 17 + b_] + xo + (dec ? bd4[3] : be4[3]);
    c_reg = c_reg * sigm(zf + 1.f) + sigm(zi) * tanh_f(zj);
    float hn = tanh_f(c_reg) * sigm(zo);
    unsigned short hb = f2bf(hn);

    // contiguous publish: thread (b_, u_) -> hbuf[buf][bg*16+b_][cs*32+u_]
    __hip_atomic_store(&hb16[((q + 1) & 1) * 32768 + (bg * 16 + b_) * 512 + cs * 32 + u_],
                       hb, __ATOMIC_RELAXED, __HIP_MEMORY_SCOPE_AGENT);
    if (dec)
      __hip_atomic_store(&hs16[(long)(tt * BATCH + bg * 16 + b_) * 512 + cs * 32 + u_],
                         hb, __ATOMIC_RELAXED, __HIP_MEMORY_SCOPE_AGENT);

    __syncthreads();   // drains vmcnt: h/hsd stores visible before flag/dcnt
    if (tid == 0)
      __hip_atomic_store(&flags[wgid * FPAD], (unsigned)(q + 2),
                         __ATOMIC_RELAXED, __HIP_MEMORY_SCOPE_AGENT);
    if (dec && tid == 64)
      __hip_atomic_fetch_add(&flags[CNT_BASE + (26 + tt) * 32], 1u,
                             __ATOMIC_RELAXED, __HIP_MEMORY_SCOPE_AGENT);
  }
}

// ---------------------------------------------------------------------------
extern "C" void kernel_launch(void* const* d_in, const int* in_sizes, int n_in,
                              void* d_out, int out_size, void* d_ws, size_t ws_size,
                              hipStream_t stream)
{
  const float* frames  = (const float*)d_in[0];
  const float* emb     = (const float*)d_in[1];
  const float* W_enc   = (const float*)d_in[2];
  const float* b_enc   = (const float*)d_in[3];
  const float* W_dec   = (const float*)d_in[4];
  const float* b_dec   = (const float*)d_in[5];
  const float* W_proj  = (const float*)d_in[6];
  const float* b_proj  = (const float*)d_in[7];
  const int*   caption = (const int*)d_in[8];

  char* ws = (char*)d_ws;
  float*          Xe    = (float*)(ws + 0);                 // 16 MB
  float*          Xd    = (float*)(ws + 16777216);          // 10 MB
  unsigned*       hbuf  = (unsigned*)(ws + 27262976);       // 128 KB (u16 x 2 buf)
  unsigned*       hsd   = (unsigned*)(ws + 27394048);       // 1.25 MB (u16)
  unsigned*       flags = (unsigned*)(ws + 28704768);       // 16 KB (flags+counters+dcnt)
  unsigned short* fbf   = (unsigned short*)(ws + 28721152); // 16.78 MB (frames bf16)
  unsigned short* wbf   = (unsigned short*)(ws + 45498368); // 16.78 MB (W_enc^T bf16)
  float* out = (float*)d_out;

  prep<<<8192, 256, 0, stream>>>(frames, W_enc, fbf, wbf, flags, Xe);
  fused<<<64 + 1184 + 80, 512, 0, stream>>>(
      fbf, wbf, Xe, emb, caption, W_dec, Xd,
      W_enc + (long)D_IN * FOURH,
      W_dec + (long)D_WORD * FOURH,
      b_enc, b_dec, W_proj, b_proj, out,
      hbuf, hsd, flags);
}

// Round 9
// 299.589 us; speedup vs baseline: 2.5715x; 1.2243x over previous
//
#include <hip/hip_runtime.h>
#include <hip/hip_bf16.h>

#define BATCH  64
#define T_ENC  32
#define D_IN   4096
#define T_DEC  20
#define D_WORD 300
#define HID    512
#define FOURH  2048
#define NWG    64
#define FPAD   32   // flags stride in u32 (128B)  [R4-proven]
#define ZP     13   // z LDS pad (f32)
// flags layout (u32 idx): [wgid*FPAD] step flags (exclusive lines);
// [2048 + i*32] i=0..15 enc bx counters, i=16..25 dec bx counters,
// i=26..45 dcnt[t] (proj gating). Total 3520 u32.
#define CNT_BASE 2048
#define FLAGS_N  3520

typedef __attribute__((ext_vector_type(8))) short short8;
typedef __attribute__((ext_vector_type(4))) float f32x4;
typedef unsigned long long ull;

static __device__ __forceinline__ unsigned short f2bf(float f){
  union { float f; unsigned u; } v; v.f = f;
  unsigned r = v.u + 0x7fffu + ((v.u >> 16) & 1u);   // RNE
  return (unsigned short)(r >> 16);
}
static __device__ __forceinline__ float bf2f(unsigned short b){
  union { unsigned u; float f; } v; v.u = ((unsigned)b) << 16;
  return v.f;
}
static __device__ __forceinline__ float sigm(float x){
  return __builtin_amdgcn_rcpf(1.f + __expf(-x));
}
static __device__ __forceinline__ float tanh_f(float x){
  float e = __expf(2.f * x);
  return 1.f - 2.f * __builtin_amdgcn_rcpf(e + 1.f);
}

// ---------------------------------------------------------------------------
// prep: frames -> bf16, W_enc input rows -> bf16 transposed, zero flags
// (incl. GEMM counters + dcnt), zero Xe (fused accumulates via atomicAdd).
// ---------------------------------------------------------------------------
__global__ __launch_bounds__(256) void prep(
    const float* __restrict__ frames, const float* __restrict__ W_enc,
    unsigned short* __restrict__ fb, unsigned short* __restrict__ wt,
    unsigned* __restrict__ flags, float* __restrict__ Xe)
{
  const int g = blockIdx.x * 256 + threadIdx.x;
  if (blockIdx.x == 0){
    for (int i = threadIdx.x; i < FLAGS_N; i += 256)
      __hip_atomic_store(&flags[i], 0u, __ATOMIC_RELAXED, __HIP_MEMORY_SCOPE_AGENT);
  }
  { // zero Xe: 4194304 floats, 2097152 threads -> float2 each
    float2 z2; z2.x = 0.f; z2.y = 0.f;
    *(float2*)(Xe + (long)g * 2) = z2;
  }
  if (g < 1048576){
    const long base = (long)g * 8;
    float4 x0 = *(const float4*)(frames + base);
    float4 x1 = *(const float4*)(frames + base + 4);
    short8 v;
    v[0] = (short)f2bf(x0.x); v[1] = (short)f2bf(x0.y);
    v[2] = (short)f2bf(x0.z); v[3] = (short)f2bf(x0.w);
    v[4] = (short)f2bf(x1.x); v[5] = (short)f2bf(x1.y);
    v[6] = (short)f2bf(x1.z); v[7] = (short)f2bf(x1.w);
    *(short8*)(fb + base) = v;
  } else {
    const int r  = g - 1048576;
    const int k0 = (r >> 11) << 3;       // 0..4088 step 8
    const int c  = r & 2047;             // coalesced reads across c
    short8 v;
#pragma unroll
    for (int j = 0; j < 8; ++j)
      v[j] = (short)f2bf(W_enc[(long)(k0 + j) * FOURH + c]);
    *(short8*)&wt[(long)c * D_IN + k0] = v;
  }
}

// ---------------------------------------------------------------------------
// Encoder tile, 8-wave (512 thr), 128x128, K-chunk = 1024 (BK=64, 16 iters),
// XOR-swizzled LDS, next-iter reg prefetch (guarded: no dead wrap load).
// Accumulates into Xe via fp32 atomicAdd, bumps per-bx counter (target 64).
// ---------------------------------------------------------------------------
__device__ __forceinline__ void enc_tile8(
    int bx, int by, int kc,
    const unsigned short* __restrict__ A0, const unsigned short* __restrict__ Wt,
    float* Z, char* smem, unsigned* flags)
{
  char* As = smem;            // [128 rows][128B], byte ^= (row&7)<<4
  char* Bs = smem + 16384;
  const int tid = threadIdx.x;
  const int row0 = bx * 128, col0 = by * 128;

  const int ar = tid >> 2, ah = tid & 3;       // A: 4 thr/row, 16 shorts each
  long asrc;
  {
    int R = row0 + ar;
    int b = R & 63, t = R >> 6;
    asrc = (long)(b * T_ENC + t) * D_IN;
  }
  const int bc = tid & 127, bh = tid >> 7;     // B: 4 thr/col
  const long bsrc = (long)(col0 + bc) * D_IN;
  const long kbase = (long)kc * 1024;

  const int wave = tid >> 6, lane = tid & 63;
  const int wm = (wave >> 2) * 64, wn = (wave & 3) * 32;
  const int lr = lane & 15, lkb = (lane >> 4) << 4, lq = (lane >> 4) << 2;

  f32x4 acc[4][2];
#pragma unroll
  for (int m = 0; m < 4; ++m)
#pragma unroll
    for (int n = 0; n < 2; ++n) acc[m][n] = (f32x4){0.f, 0.f, 0.f, 0.f};

#define ELOAD8(DA, DB, IT) do { \
    const long ka = kbase + (long)(IT) * 64 + ah * 16; \
    const long kb = kbase + (long)(IT) * 64 + bh * 16; \
    _Pragma("unroll") \
    for (int j = 0; j < 2; ++j){ \
      DA[j] = *(const short8*)(A0 + asrc + ka + j * 8); \
      DB[j] = *(const short8*)(Wt + bsrc + kb + j * 8); \
    } \
  } while (0)

  short8 aR[2], bR[2];
  ELOAD8(aR, bR, 0);

  for (int it = 0; it < 16; ++it){
    __syncthreads();   // prev iter's frag reads done
#pragma unroll
    for (int j = 0; j < 2; ++j){
      *(short8*)(As + ar * 128 + ((ah * 32 + j * 16) ^ ((ar & 7) << 4))) = aR[j];
      *(short8*)(Bs + bc * 128 + ((bh * 32 + j * 16) ^ ((bc & 7) << 4))) = bR[j];
    }
    __syncthreads();
    short8 aN[2], bN[2];
    if (it < 15) ELOAD8(aN, bN, it + 1);   // prefetch next K-block (no dead wrap)
#pragma unroll
    for (int kk = 0; kk < 2; ++kk){
      short8 af[4], bfv[2];
#pragma unroll
      for (int m = 0; m < 4; ++m){
        const int r = wm + m * 16 + lr;
        af[m] = *(const short8*)(As + r * 128 + ((kk * 64 + lkb) ^ ((r & 7) << 4)));
      }
#pragma unroll
      for (int n = 0; n < 2; ++n){
        const int r = wn + n * 16 + lr;
        bfv[n] = *(const short8*)(Bs + r * 128 + ((kk * 64 + lkb) ^ ((r & 7) << 4)));
      }
#pragma unroll
      for (int m = 0; m < 4; ++m)
#pragma unroll
        for (int n = 0; n < 2; ++n)
          acc[m][n] = __builtin_amdgcn_mfma_f32_16x16x32_bf16(af[m], bfv[n], acc[m][n], 0, 0, 0);
    }
    if (it < 15){
      aR[0] = aN[0]; aR[1] = aN[1]; bR[0] = bN[0]; bR[1] = bN[1];
    }
  }
#undef ELOAD8

#pragma unroll
  for (int m = 0; m < 4; ++m)
#pragma unroll
    for (int n = 0; n < 2; ++n)
#pragma unroll
      for (int r = 0; r < 4; ++r){
        int gr = row0 + wm + m * 16 + lq + r;
        int gc = col0 + wn + n * 16 + lr;
        __hip_atomic_fetch_add(&Z[(long)gr * FOURH + gc], acc[m][n][r],
                               __ATOMIC_RELAXED, __HIP_MEMORY_SCOPE_AGENT);
      }
  __syncthreads();   // drains vmcnt: all atomics complete before counter bump
  if (tid == 0)
    __hip_atomic_fetch_add(&flags[CNT_BASE + bx * 32], 1u,
                           __ATOMIC_RELAXED, __HIP_MEMORY_SCOPE_AGENT);
}

// ---------------------------------------------------------------------------
// Decoder tile, 8-wave (512 thr), 128x128, K=300. Coherent stores (no bias),
// bumps per-bx counter (target 16).
// ---------------------------------------------------------------------------
__device__ __forceinline__ void dec_tile8(
    int bx, int by, const float* __restrict__ emb, const int* __restrict__ cap,
    const float* __restrict__ W, float* Z, char* smem, unsigned* flags)
{
  constexpr int KLIM  = D_WORD;
  constexpr int ITERS = (KLIM + 31) / 32;
  short* As = (short*)smem;              // [128][40]
  short* Bs = (short*)(smem + 10240);
  const int tid = threadIdx.x;
  const int row0 = bx * 128, col0 = by * 128;

  const int ar = tid >> 2, akq = (tid & 3) * 8;
  long asrc;
  {
    int R = row0 + ar;
    int b = R & 63, t = R >> 6;
    asrc = (long)cap[b * T_DEC + t] * D_WORD;
  }
  const int bc = tid & 127, bkq = (tid >> 7) * 8;

  const int wave = tid >> 6, lane = tid & 63;
  const int wm = (wave >> 2) * 64, wn = (wave & 3) * 32;
  const int lr = lane & 15, lk = (lane >> 4) << 3, lq = (lane >> 4) << 2;

  f32x4 acc[4][2];
#pragma unroll
  for (int m = 0; m < 4; ++m)
#pragma unroll
    for (int n = 0; n < 2; ++n) acc[m][n] = (f32x4){0.f, 0.f, 0.f, 0.f};

  for (int it = 0; it < ITERS; ++it){
    const int k0 = it * 32;
    float av[8], bv[8];
#pragma unroll
    for (int i = 0; i < 8; ++i){
      int k = k0 + akq + i;
      av[i] = (k < KLIM) ? emb[asrc + k] : 0.f;
    }
#pragma unroll
    for (int i = 0; i < 8; ++i){
      int k = k0 + bkq + i;
      bv[i] = (k < KLIM) ? W[(long)k * FOURH + col0 + bc] : 0.f;
    }
    __syncthreads();
    short8 a8, b8;
#pragma unroll
    for (int i = 0; i < 8; ++i){
      a8[i] = (short)f2bf(av[i]);  b8[i] = (short)f2bf(bv[i]);
    }
    *(short8*)&As[ar * 40 + akq] = a8;
    *(short8*)&Bs[bc * 40 + bkq] = b8;
    __syncthreads();
    short8 af[4], bfv[2];
#pragma unroll
    for (int m = 0; m < 4; ++m) af[m]  = *(const short8*)&As[(wm + m * 16 + lr) * 40 + lk];
#pragma unroll
    for (int n = 0; n < 2; ++n) bfv[n] = *(const short8*)&Bs[(wn + n * 16 + lr) * 40 + lk];
#pragma unroll
    for (int m = 0; m < 4; ++m)
#pragma unroll
      for (int n = 0; n < 2; ++n)
        acc[m][n] = __builtin_amdgcn_mfma_f32_16x16x32_bf16(af[m], bfv[n], acc[m][n], 0, 0, 0);
  }

#pragma unroll
  for (int m = 0; m < 4; ++m)
#pragma unroll
    for (int n = 0; n < 2; ++n)
#pragma unroll
      for (int r = 0; r < 4; ++r){
        int gr = row0 + wm + m * 16 + lq + r;
        int gc = col0 + wn + n * 16 + lr;
        __hip_atomic_store(&Z[(long)gr * FOURH + gc], acc[m][n][r],
                           __ATOMIC_RELAXED, __HIP_MEMORY_SCOPE_AGENT);
      }
  __syncthreads();
  if (tid == 0)
    __hip_atomic_fetch_add(&flags[CNT_BASE + (16 + bx) * 32], 1u,
                           __ATOMIC_RELAXED, __HIP_MEMORY_SCOPE_AGENT);
}

// ---------------------------------------------------------------------------
// Projection tail block: waits on dcnt[t] == 64 (single non-critical line),
// then out[b][t][d] = hs[t][b][:] @ W_proj[:, d] + b_proj[d] for its 16 rows.
// ---------------------------------------------------------------------------
__device__ __forceinline__ void proj_tail(
    int p, const unsigned short* __restrict__ hsd, const float* __restrict__ Wp,
    const float* __restrict__ bp, float* __restrict__ out,
    unsigned* flags, char* smem)
{
  float* hl = (float*)smem;              // 16*512 f32 = 32 KB
  const int tid = threadIdx.x;
  const int r0 = p * 16;
  const int t  = r0 >> 6;                // 16 | 64 -> all 16 rows same t

  { // wait: all 64 LSTM wgs have stored hs for timestep t
    unsigned* dc = &flags[CNT_BASE + (26 + t) * 32];
    while (__hip_atomic_load(dc, __ATOMIC_RELAXED, __HIP_MEMORY_SCOPE_AGENT) < 64u)
      __builtin_amdgcn_s_sleep(16);
  }
  __builtin_amdgcn_sched_barrier(0);

  for (int idx = tid; idx < 16 * 512; idx += 512)
    hl[idx] = bf2f(hsd[(long)r0 * 512 + idx]);
  __syncthreads();
  if (tid < D_WORD){
    const int d = tid;
    float acc[16];
#pragma unroll
    for (int r = 0; r < 16; ++r) acc[r] = bp[d];
    for (int k = 0; k < 512; ++k){
      float w = Wp[k * D_WORD + d];
#pragma unroll
      for (int r = 0; r < 16; ++r) acc[r] += hl[r * 512 + k] * w;
    }
#pragma unroll
    for (int r = 0; r < 16; ++r){
      int R = r0 + r;
      int tt = R >> 6, b = R & 63;
      out[(long)(b * T_DEC + tt) * D_WORD + d] = acc[r];
    }
  }
}

// ---------------------------------------------------------------------------
// Persistent LSTM recurrence core (R4 champion, 295 us): h-exchange is
// DIRECT global->reg (each fragment read exactly once -> no LDS relay,
// 2 barriers/step). hbuf is wg-major: [buf][wgid][b][8] u16 so each wg's
// per-step 1KB h-slice store is contiguous and line-private (fast vmcnt
// drain, no cross-wg false sharing). setprio(1) scoped to the MFMA cluster.
// ---------------------------------------------------------------------------
#define REC_GEMM(WREG) do { \
  _Pragma("unroll") \
  for (int kk = 0; kk < 8; ++kk){ \
    short8 af; \
    ((ull*)&af)[0] = ha[2 * kk]; \
    ((ull*)&af)[1] = ha[2 * kk + 1]; \
    _Pragma("unroll") \
    for (int n = 0; n < 2; ++n) \
      acc[n] = __builtin_amdgcn_mfma_f32_16x16x32_bf16(af, WREG[kk][n], acc[n], 0, 0, 0); \
  } \
} while (0)

// ---------------------------------------------------------------------------
// Fused kernel: bids 0..63 = persistent LSTM; 64..1247 = input-GEMM tiles
// (enc bx0..7, then dec, then enc bx8..15); 1248..1327 = projection tails.
// ---------------------------------------------------------------------------
__global__ __launch_bounds__(512, 1) void fused(
    const unsigned short* __restrict__ fbf, const unsigned short* __restrict__ wbf,
    float* Xe,
    const float* __restrict__ emb, const int* __restrict__ cap,
    const float* __restrict__ W_dec, float* Xd,
    const float* __restrict__ Wre, const float* __restrict__ Wrd,
    const float* __restrict__ b_enc, const float* __restrict__ b_dec,
    const float* __restrict__ Wp, const float* __restrict__ bp,
    float* __restrict__ out,
    unsigned* hbuf_u, unsigned* hsd_u, unsigned* flags)
{
  __shared__ __align__(16) char smem[65536];
  const int bid = blockIdx.x;

  if (bid >= 64){
    int g = bid - 64;
    if (g < 512)        enc_tile8(g >> 6, g & 15, (g >> 4) & 3, fbf, wbf, Xe, smem, flags);
    else if (g < 672){  int d = g - 512; dec_tile8(d >> 4, d & 15, emb, cap, W_dec, Xd, smem, flags); }
    else if (g < 1184){ int e = g - 672; enc_tile8(8 + (e >> 6), e & 15, (e >> 4) & 3, fbf, wbf, Xe, smem, flags); }
    else                proj_tail(g - 1184, (const unsigned short*)hsd_u, Wp, bp, out, flags, smem);
    return;
  }

  // ---------------- persistent LSTM block ----------------
  float* zlds = (float*)smem;              // 26.6 KB gate partials (only LDS use)
  const int tid = threadIdx.x, wgid = bid;
  const int wave = tid >> 6, lane = tid & 63;
  const int kh = wave >> 2, mh = wave & 3;
  const int lr = lane & 15, lk = (lane >> 4) << 3;
  const int hi = lane >> 4, lq = (lane >> 4) << 2;

  int ocol[2];
#pragma unroll
  for (int n = 0; n < 2; ++n)
    ocol[n] = (n * 2 + (lr >> 3)) * 512 + wgid * 8 + (lr & 7);

  short8 we[8][2], wd[8][2];
#pragma unroll
  for (int kk = 0; kk < 8; ++kk)
#pragma unroll
    for (int n = 0; n < 2; ++n){
      short8 e, d;
#pragma unroll
      for (int j = 0; j < 8; ++j){
        int k = kh * 256 + kk * 32 + lk + j;
        e[j] = (short)f2bf(Wre[(long)k * FOURH + ocol[n]]);
        d[j] = (short)f2bf(Wrd[(long)k * FOURH + ocol[n]]);
      }
      we[kk][n] = e; wd[kk][n] = d;
    }

  const int cb_ = tid >> 3, cu = tid & 7;
  float c_reg = 0.f;

  float be4[4], bd4[4];
#pragma unroll
  for (int gg = 0; gg < 4; ++gg){
    be4[gg] = b_enc[gg * 512 + wgid * 8 + cu];
    bd4[gg] = b_dec[gg * 512 + wgid * 8 + cu];
  }

  // zero own slice of buffer 0 (wg-major: ull idx wgid*128 + 0..127)
  if (tid < 128)
    __hip_atomic_store((ull*)hbuf_u + wgid * 128 + tid, 0ull,
                       __ATOMIC_RELAXED, __HIP_MEMORY_SCOPE_AGENT);
  __syncthreads();
  if (tid == 0)
    __hip_atomic_store(&flags[wgid * FPAD], 1u,
                       __ATOMIC_RELAXED, __HIP_MEMORY_SCOPE_AGENT);

  const bool mine = (lane != wgid);

  // per-thread ull offsets of the 8 h-fragments (4 consecutive ulls each)
  int off8[8];
#pragma unroll
  for (int kk = 0; kk < 8; ++kk)
    off8[kk] = (kh * 32 + kk * 4 + hi) * 128 + (mh * 16 + lr) * 2;

  for (int q = 0; q < T_ENC + T_DEC; ++q){
    const bool dec = (q >= T_ENC);
    const int tt = dec ? q - T_ENC : q;
    float* Xp = dec ? Xd : Xe;

    // wait for the input-GEMM columns feeding this timestep (counter is
    // monotonic and covers 2 timesteps -> only poll on even tt)
    if (!(tt & 1)){
      unsigned* xc = dec ? &flags[CNT_BASE + (16 + (tt >> 1)) * 32]
                         : &flags[CNT_BASE + (tt >> 1) * 32];
      const unsigned xtgt = dec ? 16u : 64u;
      while (__hip_atomic_load(xc, __ATOMIC_RELAXED, __HIP_MEMORY_SCOPE_AGENT) < xtgt)
        __builtin_amdgcn_s_sleep(2);
    }
    __builtin_amdgcn_sched_barrier(0);

    const long xb = (long)(tt * BATCH + cb_) * FOURH + wgid * 8 + cu;
    float xi = __hip_atomic_load(&Xp[xb],        __ATOMIC_RELAXED, __HIP_MEMORY_SCOPE_AGENT);
    float xj = __hip_atomic_load(&Xp[xb +  512], __ATOMIC_RELAXED, __HIP_MEMORY_SCOPE_AGENT);
    float xf = __hip_atomic_load(&Xp[xb + 1024], __ATOMIC_RELAXED, __HIP_MEMORY_SCOPE_AGENT);
    float xo = __hip_atomic_load(&Xp[xb + 1536], __ATOMIC_RELAXED, __HIP_MEMORY_SCOPE_AGENT);

    {
      const unsigned tgt = (unsigned)(q + 1);
      for (;;){
        unsigned f = tgt;
        if (mine) f = __hip_atomic_load(&flags[lane * FPAD],
                                        __ATOMIC_RELAXED, __HIP_MEMORY_SCOPE_AGENT);
        if (__all((int)(f >= tgt))) break;
        __builtin_amdgcn_s_sleep(1);
      }
    }
    __builtin_amdgcn_sched_barrier(0);

    // direct h fragment loads: fragment (kk,hi) lives in owner wg
    // w = kh*32 + kk*4 + hi at ull idx w*128 + (mh*16+lr)*2 (+1)
    const ull* rb = (const ull*)hbuf_u + (q & 1) * 8192;
    ull ha[16];
#pragma unroll
    for (int kk = 0; kk < 8; ++kk){
      const int o = off8[kk];
      ha[2 * kk]     = __hip_atomic_load(rb + o,     __ATOMIC_RELAXED, __HIP_MEMORY_SCOPE_AGENT);
      ha[2 * kk + 1] = __hip_atomic_load(rb + o + 1, __ATOMIC_RELAXED, __HIP_MEMORY_SCOPE_AGENT);
    }

    f32x4 acc[2];
#pragma unroll
    for (int n = 0; n < 2; ++n) acc[n] = (f32x4){0.f, 0.f, 0.f, 0.f};
    __builtin_amdgcn_s_setprio(1);
    if (!dec) REC_GEMM(we); else REC_GEMM(wd);
    __builtin_amdgcn_s_setprio(0);

#pragma unroll
    for (int n = 0; n < 2; ++n){
      const int g = n * 2 + (lr >> 3), u = lr & 7;
#pragma unroll
      for (int r = 0; r < 4; ++r){
        const int row = mh * 16 + lq + r;
        zlds[((kh * 4 + g) * 64 + row) * ZP + u] = acc[n][r];
      }
    }
    __syncthreads();

    const int zb = cb_ * ZP + cu;
    float zi = zlds[(0 * 64) * ZP + zb] + zlds[(4 * 64) * ZP + zb] + xi + (dec ? bd4[0] : be4[0]);
    float zj = zlds[(1 * 64) * ZP + zb] + zlds[(5 * 64) * ZP + zb] + xj + (dec ? bd4[1] : be4[1]);
    float zf = zlds[(2 * 64) * ZP + zb] + zlds[(6 * 64) * ZP + zb] + xf + (dec ? bd4[2] : be4[2]);
    float zo = zlds[(3 * 64) * ZP + zb] + zlds[(7 * 64) * ZP + zb] + xo + (dec ? bd4[3] : be4[3]);
    c_reg = c_reg * sigm(zf + 1.f) + sigm(zi) * tanh_f(zj);
    float hn = tanh_f(c_reg) * sigm(zo);
    unsigned short hb = f2bf(hn);

    // wg-major h store: contiguous 1KB per wg (u16 idx = buf*32768 + wgid*512 + tid)
    __hip_atomic_store(&((unsigned short*)hbuf_u)[((q + 1) & 1) * 32768 + wgid * 512 + tid],
                       hb, __ATOMIC_RELAXED, __HIP_MEMORY_SCOPE_AGENT);
    if (dec)
      __hip_atomic_store(&((unsigned short*)hsd_u)[(tt * BATCH + cb_) * 512 + wgid * 8 + cu],
                         hb, __ATOMIC_RELAXED, __HIP_MEMORY_SCOPE_AGENT);

    __syncthreads();   // drains vmcnt: h/hsd stores visible before flag/dcnt
    if (tid == 0)
      __hip_atomic_store(&flags[wgid * FPAD], (unsigned)(q + 2),
                         __ATOMIC_RELAXED, __HIP_MEMORY_SCOPE_AGENT);
    if (dec && tid == 64)
      __hip_atomic_fetch_add(&flags[CNT_BASE + (26 + tt) * 32], 1u,
                             __ATOMIC_RELAXED, __HIP_MEMORY_SCOPE_AGENT);
  }
}

// ---------------------------------------------------------------------------
extern "C" void kernel_launch(void* const* d_in, const int* in_sizes, int n_in,
                              void* d_out, int out_size, void* d_ws, size_t ws_size,
                              hipStream_t stream)
{
  const float* frames  = (const float*)d_in[0];
  const float* emb     = (const float*)d_in[1];
  const float* W_enc   = (const float*)d_in[2];
  const float* b_enc   = (const float*)d_in[3];
  const float* W_dec   = (const float*)d_in[4];
  const float* b_dec   = (const float*)d_in[5];
  const float* W_proj  = (const float*)d_in[6];
  const float* b_proj  = (const float*)d_in[7];
  const int*   caption = (const int*)d_in[8];

  char* ws = (char*)d_ws;
  float*          Xe    = (float*)(ws + 0);                 // 16 MB
  float*          Xd    = (float*)(ws + 16777216);          // 10 MB
  unsigned*       hbuf  = (unsigned*)(ws + 27262976);       // 128 KB (u16 x 2 buf)
  unsigned*       hsd   = (unsigned*)(ws + 27394048);       // 1.25 MB (u16)
  unsigned*       flags = (unsigned*)(ws + 28704768);       // 16 KB (flags+counters+dcnt)
  unsigned short* fbf   = (unsigned short*)(ws + 28721152); // 16.78 MB (frames bf16)
  unsigned short* wbf   = (unsigned short*)(ws + 45498368); // 16.78 MB (W_enc^T bf16)
  float* out = (float*)d_out;

  prep<<<8192, 256, 0, stream>>>(frames, W_enc, fbf, wbf, flags, Xe);
  fused<<<64 + 1184 + 80, 512, 0, stream>>>(
      fbf, wbf, Xe, emb, caption, W_dec, Xd,
      W_enc + (long)D_IN * FOURH,
      W_dec + (long)D_WORD * FOURH,
      b_enc, b_dec, W_proj, b_proj, out,
      hbuf, hsd, flags);
}